// Round 6
// baseline (928.932 us; speedup 1.0000x reference)
//
#include <hip/hip_runtime.h>
#include <stdint.h>

typedef __attribute__((ext_vector_type(8))) short bf16x8;
typedef __attribute__((ext_vector_type(4))) float f32x4;
typedef __attribute__((ext_vector_type(4))) short short4v;

#define DEV __device__ __forceinline__
#define L2E 1.4426950408889634f

DEV float bf2f(unsigned short s){ union{unsigned int u; float f;} x; x.u = ((unsigned int)s)<<16; return x.f; }
DEV unsigned short f2bf(float f){ union{float f; unsigned int u;} x; x.f = f; x.u += 0x7fffu + ((x.u>>16)&1u); return (unsigned short)(x.u>>16); }

DEV f32x4 mfma16(bf16x8 a, bf16x8 b, f32x4 c){
  return __builtin_amdgcn_mfma_f32_16x16x32_bf16(a, b, c, 0, 0, 0);
}
DEV f32x4 zero4(){ f32x4 z; z[0]=0.f; z[1]=0.f; z[2]=0.f; z[3]=0.f; return z; }
DEV bf16x8 zerob(){ bf16x8 z; z[0]=0;z[1]=0;z[2]=0;z[3]=0;z[4]=0;z[5]=0;z[6]=0;z[7]=0; return z; }
DEV float fexp2(float x){ float r; asm volatile("v_exp_f32 %0, %1" : "=v"(r) : "v"(x)); return r; }
DEV void barw(){ asm volatile("s_waitcnt lgkmcnt(0)" ::: "memory"); __builtin_amdgcn_s_barrier(); }

// ---------------- elementwise f32 -> bf16 ----------------
__global__ __launch_bounds__(256) void k_f32_to_bf16(const float* __restrict__ in, unsigned short* __restrict__ out, int n4){
  int i = blockIdx.x*256 + threadIdx.x;
  if (i < n4){
    float4 v = ((const float4*)in)[i];
    short4v o; o.x=(short)f2bf(v.x); o.y=(short)f2bf(v.y); o.z=(short)f2bf(v.z); o.w=(short)f2bf(v.w);
    ((short4v*)out)[i] = o;
  }
}

// ------------- f32 [R][C] -> bf16 transposed [C][R] -------------
__global__ __launch_bounds__(256) void k_convT(const float* __restrict__ in, unsigned short* __restrict__ out, int R, int Cc){
  __shared__ float t[32][33];
  int c0 = blockIdx.x*32, r0 = blockIdx.y*32;
  int tid = threadIdx.x;
  int row = tid>>3, col4 = (tid&7)*4;
  float4 v = *(const float4*)&in[(size_t)(r0+row)*Cc + c0 + col4];
  t[row][col4+0]=v.x; t[row][col4+1]=v.y; t[row][col4+2]=v.z; t[row][col4+3]=v.w;
  __syncthreads();
  short4v o;
  o.x=(short)f2bf(t[col4+0][row]); o.y=(short)f2bf(t[col4+1][row]);
  o.z=(short)f2bf(t[col4+2][row]); o.w=(short)f2bf(t[col4+3][row]);
  *(short4v*)&out[(size_t)(c0+row)*R + r0 + col4] = o;
}

// ------------- small prep -------------
__global__ __launch_bounds__(256) void k_prep(const float* __restrict__ wpre, const float* __restrict__ wpost,
                                              const float* __restrict__ temp,
                                              unsigned short* __restrict__ wpre_t,
                                              unsigned short* __restrict__ wpre_t2,
                                              unsigned short* __restrict__ wpost_b){
  int t = threadIdx.x;
  float T = temp[0];
  wpre_t[t]  = f2bf(wpre[t]*T);
  wpre_t2[t] = f2bf(wpre[t]*T*L2E);
  wpost_b[t] = f2bf(wpost[t]);
}

// ------------- mask bytes -> f32 addend -------------
__global__ __launch_bounds__(256) void k_maskf(const unsigned char* __restrict__ mask, float* __restrict__ maskf){
  int i = blockIdx.x*256 + threadIdx.x;
  if (i < 4096) maskf[i] = mask[i] ? -1e30f : 0.f;
}

// ------------- GEMM -------------
template<int OUTF>
__global__ __launch_bounds__(256,2) void k_gemm(const unsigned short* __restrict__ A, const unsigned short* __restrict__ Bt,
                                                void* __restrict__ Cv, int M, int Nn, int K){
  __shared__ unsigned short As[128][72];
  __shared__ unsigned short Bs[128][72];
  int tid = threadIdx.x;
  int n0 = blockIdx.x*128, m0 = blockIdx.y*128;
  int w = tid>>6, lane = tid&63, lg = lane>>4, lp = lane&15;
  int wm = (w>>1)*64, wn = (w&1)*64;
  f32x4 acc[4][4];
  #pragma unroll
  for (int i=0;i<4;++i)
    #pragma unroll
    for (int j=0;j<4;++j) acc[i][j] = zero4();

  for (int kt=0; kt<K; kt+=64){
    #pragma unroll
    for (int cch=0; cch<4; ++cch){
      int e = tid + cch*256; int r = e>>3, cl = (e&7)*8;
      *(bf16x8*)&As[r][cl] = *(const bf16x8*)&A[(size_t)(m0+r)*K + kt + cl];
      *(bf16x8*)&Bs[r][cl] = *(const bf16x8*)&Bt[(size_t)(n0+r)*K + kt + cl];
    }
    __syncthreads();
    #pragma unroll
    for (int ks=0; ks<2; ++ks){
      bf16x8 a[4], b[4];
      #pragma unroll
      for (int mi=0; mi<4; ++mi) a[mi] = *(const bf16x8*)&As[wm+mi*16+lp][ks*32 + lg*8];
      #pragma unroll
      for (int ni=0; ni<4; ++ni) b[ni] = *(const bf16x8*)&Bs[wn+ni*16+lp][ks*32 + lg*8];
      #pragma unroll
      for (int mi=0; mi<4; ++mi)
        #pragma unroll
        for (int ni=0; ni<4; ++ni)
          acc[mi][ni] = mfma16(a[mi], b[ni], acc[mi][ni]);
    }
    __syncthreads();
  }
  #pragma unroll
  for (int mi=0; mi<4; ++mi)
    #pragma unroll
    for (int ni=0; ni<4; ++ni)
      #pragma unroll
      for (int r=0; r<4; ++r){
        int row = m0+wm+mi*16+lg*4+r, col = n0+wn+ni*16+lp;
        if (OUTF) ((float*)Cv)[(size_t)row*Nn+col] = acc[mi][ni][r];
        else ((unsigned short*)Cv)[(size_t)row*Nn+col] = f2bf(acc[mi][ni][r]);
      }
}

// ------------- split qkv, l2norm q/k -------------
__global__ __launch_bounds__(256) void k_split_norm(const unsigned short* __restrict__ qkv,
                                                    unsigned short* __restrict__ q, unsigned short* __restrict__ k,
                                                    unsigned short* __restrict__ v, float* __restrict__ kv_out){
  int w = threadIdx.x>>6, lane = threadIdx.x&63;
  int widx = blockIdx.x*4 + w;
  int h = widx & 15; int bn = widx >> 4;
  int b = bn >> 11; int n = bn & 2047;
  size_t base = (size_t)bn*3072 + h*192 + lane*3;
  float qv = bf2f(qkv[base]), kvv = bf2f(qkv[base+1]), vv = bf2f(qkv[base+2]);
  float nq = qv*qv, nk = kvv*kvv;
  #pragma unroll
  for (int m=1; m<64; m<<=1){ nq += __shfl_xor(nq, m); nk += __shfl_xor(nk, m); }
  float qn = qv / fmaxf(sqrtf(nq), 1e-12f);
  float kn = kvv / fmaxf(sqrtf(nk), 1e-12f);
  size_t idx = ((size_t)(b*16+h)*2048 + n)*64 + lane;
  q[idx] = f2bf(qn); k[idx] = f2bf(kn); v[idx] = f2bf(vv);
  kv_out[idx] = kn;
  kv_out[4194304 + idx] = vv;
}

// ------------- v -> vt transposed -------------
__global__ __launch_bounds__(256) void k_transpose_v(const unsigned short* __restrict__ v, unsigned short* __restrict__ vt){
  __shared__ unsigned short t[64][72];
  int bh = blockIdx.y; int n0 = blockIdx.x*64;
  int tid = threadIdx.x;
  #pragma unroll
  for (int cch=0; cch<2; ++cch){
    int e = tid + cch*256; int r = e>>3, c8 = (e&7)*8;
    *(bf16x8*)&t[r][c8] = *(const bf16x8*)&v[((size_t)bh*2048 + n0 + r)*64 + c8];
  }
  __syncthreads();
  #pragma unroll
  for (int cch=0; cch<2; ++cch){
    int e = tid + cch*256; int d = e>>3, nn8 = (e&7)*8;
    bf16x8 o;
    #pragma unroll
    for (int i=0;i<8;++i) o[i] = (short)t[nn8+i][d];
    *(bf16x8*)&vt[((size_t)bh*64 + d)*2048 + n0 + nn8] = o;
  }
}

// ------------- vsum -------------
__global__ __launch_bounds__(256) void k_vsum(const unsigned short* __restrict__ v, float* __restrict__ vsum){
  int bg = blockIdx.x;
  int d = threadIdx.x & 63, part = threadIdx.x>>6;
  float s = 0.f;
  for (int n = part*512; n < part*512+512; ++n) s += bf2f(v[((size_t)bg*2048 + n)*64 + d]);
  __shared__ float red[4][64];
  red[part][d] = s; __syncthreads();
  if (part==0) vsum[bg*64 + d] = red[0][d]+red[1][d]+red[2][d]+red[3][d];
}

// =================================================================
// k_score: single sweep; pb/mask pipelined one tile ahead; S double-buffered
// grid 1024: bid -> (b, it, js4). LDS = 2 x (512 rows x 40B) = 40KB.
// =================================================================
__global__ __launch_bounds__(512,4) void k_score(
    const unsigned short* __restrict__ q,
    const unsigned short* __restrict__ kk,
    const float* __restrict__ pos_bias,
    const float* __restrict__ maskf,
    const unsigned short* __restrict__ wpre_t2,
    const float* __restrict__ bpre,
    unsigned short* __restrict__ Pb,
    float* __restrict__ part_l)
{
  __shared__ __align__(16) char smem[40960];
  const int tid = threadIdx.x;
  const int w = tid>>6, lane = tid&63, lg = lane>>4, lp = lane&15;
  const int bid = blockIdx.x;
  const int qd = bid>>4, r2 = bid&15;
  const int b = r2>>3, n = qd*8 + (r2&7);
  const int it = n>>2, js = n&3;
  const int i0 = it*16, jsb = js*512;

  bf16x8 qf[2][2];
  #pragma unroll
  for (int hh=0; hh<2; ++hh){
    const unsigned short* qb = q + ((size_t)(b*16+2*w+hh)*2048 + i0 + lp)*64;
    qf[hh][0] = *(const bf16x8*)(qb + lg*8);
    qf[hh][1] = *(const bf16x8*)(qb + 32 + lg*8);
  }
  bf16x8 preA = zerob();
  if (lg < 2) preA = *(const bf16x8*)&wpre_t2[lp*16 + lg*8];
  float bpre_s[4];
  #pragma unroll
  for (int r=0;r<4;++r) bpre_s[r] = bpre[lg*4+r]*L2E - 32.0f;

  float sacc[2][4];
  #pragma unroll
  for (int ii=0;ii<2;++ii)
    #pragma unroll
    for (int r=0;r<4;++r) sacc[ii][r] = 0.f;

  const size_t kbase0 = (size_t)(b*16 + 2*w)*131072;
  const size_t kbase1 = (size_t)(b*16 + 2*w+1)*131072;

  // prefetch K(0), pb(0), mask(0)
  bf16x8 k0v[4], k1v[4];
  #pragma unroll
  for (int kf=0; kf<2; ++kf)
    #pragma unroll
    for (int jf=0; jf<2; ++jf){
      size_t off = (size_t)(jsb + jf*16 + lp)*64 + kf*32 + lg*8;
      k0v[kf*2+jf] = *(const bf16x8*)(kk + kbase0 + off);
      k1v[kf*2+jf] = *(const bf16x8*)(kk + kbase1 + off);
    }
  float pbA[4][4], pbB[4][4];
  float mkA0, mkA1, mkB0, mkB1;
  #pragma unroll
  for (int cc=0; cc<4; ++cc){
    int il = 2*w + (cc>>1);
    int jl = (cc&1)*16 + lp;
    #pragma unroll
    for (int r=0;r<4;++r)
      pbA[cc][r] = pos_bias[(size_t)(lg*4+r)*4194304 + (size_t)(i0+il)*2048 + jsb + jl];
  }
  mkA0 = maskf[b*2048 + jsb + lp];
  mkA1 = maskf[b*2048 + jsb + 16 + lp];

#define SCORE_TILE(T, PBC, PBN, MC0, MC1, MN0, MN1) do { \
    const int j0 = jsb + (T)*32; \
    const int j0n = jsb + (((T)+1)&15)*32; \
    char* sbuf = smem + ((T)&1)*20480; \
    f32x4 s0[2], s1[2]; \
    _Pragma("unroll") \
    for (int jf=0;jf<2;++jf){ s0[jf]=zero4(); s1[jf]=zero4(); } \
    _Pragma("unroll") \
    for (int kf=0; kf<2; ++kf) \
      _Pragma("unroll") \
      for (int jf=0; jf<2; ++jf){ \
        s0[jf] = mfma16(qf[0][kf], k0v[kf*2+jf], s0[jf]); \
        s1[jf] = mfma16(qf[1][kf], k1v[kf*2+jf], s1[jf]); \
      } \
    _Pragma("unroll") \
    for (int jf=0;jf<2;++jf) \
      _Pragma("unroll") \
      for (int r=0;r<4;++r){ \
        int ij = (lg*4+r)*32 + jf*16 + lp; \
        unsigned int pk = (unsigned int)f2bf(s0[jf][r]) | ((unsigned int)f2bf(s1[jf][r])<<16); \
        *(unsigned int*)(sbuf + ij*40 + w*4) = pk; \
      } \
    _Pragma("unroll") \
    for (int kf=0; kf<2; ++kf) \
      _Pragma("unroll") \
      for (int jf=0; jf<2; ++jf){ \
        size_t off = (size_t)(j0n + jf*16 + lp)*64 + kf*32 + lg*8; \
        k0v[kf*2+jf] = *(const bf16x8*)(kk + kbase0 + off); \
        k1v[kf*2+jf] = *(const bf16x8*)(kk + kbase1 + off); \
      } \
    barw(); \
    _Pragma("unroll") \
    for (int cc=0; cc<4; ++cc){ \
      int il = 2*w + (cc>>1); \
      int jl = (cc&1)*16 + lp; \
      _Pragma("unroll") \
      for (int r=0;r<4;++r) \
        PBN[cc][r] = pos_bias[(size_t)(lg*4+r)*4194304 + (size_t)(i0+il)*2048 + j0n + jl]; \
    } \
    MN0 = maskf[b*2048 + j0n + lp]; \
    MN1 = maskf[b*2048 + j0n + 16 + lp]; \
    _Pragma("unroll") \
    for (int cc=0; cc<4; ++cc){ \
      int c = w*4+cc; \
      int il = 2*w + (cc>>1); \
      int jl = (cc&1)*16 + lp; \
      bf16x8 sfrag = zerob(); \
      if (lg < 2) sfrag = *(const bf16x8*)(sbuf + (c*16+lp)*40 + lg*16); \
      f32x4 pa = mfma16(preA, sfrag, zero4()); \
      float mkj = (cc&1) ? MC1 : MC0; \
      short4v p4; \
      float pv[4]; \
      _Pragma("unroll") \
      for (int r=0;r<4;++r){ \
        float e = fmaf(PBC[cc][r], L2E, pa[r] + bpre_s[r] + mkj); \
        pv[r] = fexp2(e); \
        sacc[cc>>1][r] += pv[r]; \
      } \
      p4.x = (short)f2bf(pv[0]); p4.y = (short)f2bf(pv[1]); \
      p4.z = (short)f2bf(pv[2]); p4.w = (short)f2bf(pv[3]); \
      *(short4v*)&Pb[(((size_t)(b*2048 + i0+il)*2048) + j0 + jl)*16 + lg*4] = p4; \
    } \
  } while(0)

  for (int tt=0; tt<8; ++tt){
    SCORE_TILE(2*tt,   pbA, pbB, mkA0, mkA1, mkB0, mkB1);
    SCORE_TILE(2*tt+1, pbB, pbA, mkB0, mkB1, mkA0, mkA1);
  }
#undef SCORE_TILE

  #pragma unroll
  for (int ii=0;ii<2;++ii)
    #pragma unroll
    for (int r=0;r<4;++r){
      float v = sacc[ii][r];
      #pragma unroll
      for (int m=1; m<16; m<<=1) v += __shfl_xor(v, m);
      sacc[ii][r] = v;
    }
  if (lp == 0){
    int base = ((b*128+it)*4 + js)*256;
    #pragma unroll
    for (int ii=0;ii<2;++ii){
      float4 st; st.x = sacc[ii][0]; st.y = sacc[ii][1]; st.z = sacc[ii][2]; st.w = sacc[ii][3];
      *(float4*)&part_l[base + (2*w+ii)*16 + lg*4] = st;
    }
  }
}

// =================================================================
// k_mix: postmix (Wpost/l) + PV; Pb pipelined one tile ahead; Al double-buffered
// grid 512: bid -> (b, it, js2). LDS = 2x16KB Al + 1KB linv.
// =================================================================
__global__ __launch_bounds__(512,4) void k_mix(
    const unsigned short* __restrict__ Pb,
    const unsigned short* __restrict__ vt,
    const unsigned short* __restrict__ wpost_b,
    const float* __restrict__ bpost,
    const float* __restrict__ vsum,
    const float* __restrict__ part_l,
    float* __restrict__ pout0,
    float* __restrict__ pout1)
{
  __shared__ __align__(16) char smem[33792];
  float* linv = (float*)(smem + 32768);
  const int tid = threadIdx.x;
  const int w = tid>>6, lane = tid&63, lg = lane>>4, lp = lane&15;
  const int bid = blockIdx.x;
  const int qd = bid>>4, r2 = bid&15;
  const int b = r2>>3, n = qd*8 + (r2&7);
  const int it = n>>1, js = n&1;
  const int i0 = it*16, jsb = js*1024;

  if (tid < 256){
    int base = ((b*128+it)*4)*256 + tid;
    float sum = part_l[base] + part_l[base+256] + part_l[base+512] + part_l[base+768];
    linv[tid] = 1.f/sum;
  }
  __syncthreads();

  bf16x8 postB[2];
  #pragma unroll
  for (int ii=0;ii<2;++ii){
    postB[ii] = zerob();
    if (lg < 2){
      bf16x8 wf = *(const bf16x8*)&wpost_b[lp*16 + lg*8];
      int i = 2*w+ii;
      #pragma unroll
      for (int e=0;e<8;++e){
        float vsc = bf2f((unsigned short)wf[e]) * linv[i*16 + lg*8 + e];
        postB[ii][e] = (short)f2bf(vsc);
      }
    }
  }

  f32x4 oacc[2][4];
  #pragma unroll
  for (int hh=0; hh<2; ++hh)
    #pragma unroll
    for (int df=0; df<4; ++df) oacc[hh][df] = zero4();

  // prefetch Pb(0)
  bf16x8 pbC[4], pbN[4];
  #pragma unroll
  for (int cc=0; cc<4; ++cc){
    pbC[cc] = zerob();
    int il = 2*w + (cc>>1);
    if (lg < 2)
      pbC[cc] = *(const bf16x8*)&Pb[(((size_t)(b*2048 + i0+il)*2048) + jsb + (cc&1)*16 + lp)*16 + lg*8];
  }

#define MIX_TILE(T, PC, PN) do { \
    const int j0 = jsb + (T)*32; \
    const int j0n = jsb + (((T)+1)&31)*32; \
    char* abuf = smem + ((T)&1)*16384; \
    bf16x8 vfr[2][4]; \
    _Pragma("unroll") \
    for (int hh=0; hh<2; ++hh) \
      _Pragma("unroll") \
      for (int df=0; df<4; ++df) \
        vfr[hh][df] = *(const bf16x8*)(vt + ((size_t)(b*16+2*w+hh)*64 + df*16 + lp)*2048 + j0 + lg*8); \
    _Pragma("unroll") \
    for (int cc=0; cc<4; ++cc){ \
      int il = 2*w + (cc>>1); \
      f32x4 aa = mfma16(PC[cc], postB[cc>>1], zero4()); \
      short4v av; \
      av.x = (short)f2bf(aa[0]); av.y = (short)f2bf(aa[1]); \
      av.z = (short)f2bf(aa[2]); av.w = (short)f2bf(aa[3]); \
      int row = lp*16 + il; \
      int chunk = ((cc&1)*4 + lg) ^ ((lp ^ il)&6); \
      *(short4v*)(abuf + row*64 + chunk*8) = av; \
    } \
    _Pragma("unroll") \
    for (int cc=0; cc<4; ++cc){ \
      int il = 2*w + (cc>>1); \
      PN[cc] = zerob(); \
      if (lg < 2) \
        PN[cc] = *(const bf16x8*)&Pb[(((size_t)(b*2048 + i0+il)*2048) + j0n + (cc&1)*16 + lp)*16 + lg*8]; \
    } \
    barw(); \
    _Pragma("unroll") \
    for (int hh=0; hh<2; ++hh){ \
      int gg = 2*w+hh; \
      int rrow = gg*16+lp; \
      bf16x8 af = *(const bf16x8*)(abuf + rrow*64 + (((lg*2) ^ ((gg^lp)&6))*8)); \
      _Pragma("unroll") \
      for (int df=0; df<4; ++df) \
        oacc[hh][df] = mfma16(af, vfr[hh][df], oacc[hh][df]); \
    } \
  } while(0)

  for (int tt=0; tt<16; ++tt){
    MIX_TILE(2*tt,   pbC, pbN);
    MIX_TILE(2*tt+1, pbN, pbC);
  }
#undef MIX_TILE

  float* po = js ? pout1 : pout0;
  #pragma unroll
  for (int hh=0; hh<2; ++hh){
    int gg = 2*w+hh;
    float bp = (js==0) ? bpost[gg] : 0.f;
    #pragma unroll
    for (int df=0; df<4; ++df){
      int d = df*16+lp;
      float vs = vsum[(b*16+gg)*64 + d];
      #pragma unroll
      for (int r=0;r<4;++r){
        po[((size_t)b*2048 + i0 + lg*4 + r)*1024 + gg*64 + d] = oacc[hh][df][r] + bp*vs;
      }
    }
  }
}

// ------------- combine partial outputs -> bf16 attn_out -------------
__global__ __launch_bounds__(256) void k_combine(const float* __restrict__ p0, const float* __restrict__ p1,
                                                 unsigned short* __restrict__ ao){
  int i = blockIdx.x*256 + threadIdx.x;
  float4 a = ((const float4*)p0)[i];
  float4 c = ((const float4*)p1)[i];
  short4v o;
  o.x=(short)f2bf(a.x+c.x); o.y=(short)f2bf(a.y+c.y);
  o.z=(short)f2bf(a.z+c.z); o.w=(short)f2bf(a.w+c.w);
  ((short4v*)ao)[i] = o;
}

// =================================================================
// OLD PATH (fallback for small ws): two-pass recompute
// =================================================================
__global__ __launch_bounds__(512,6) void k_pass1f(
    const unsigned short* __restrict__ q,
    const unsigned short* __restrict__ kk,
    const float* __restrict__ pos_bias,
    const unsigned char* __restrict__ mask,
    const unsigned short* __restrict__ wpre_t,
    const float* __restrict__ bpre,
    float* __restrict__ part_m,
    float* __restrict__ part_l)
{
  __shared__ __align__(16) char smem[40960];
  const int tid = threadIdx.x;
  const int w = tid>>6, lane = tid&63, lg = lane>>4, lp = lane&15;
  const int bid = blockIdx.x;
  const int js = bid & 3, b = (bid>>2)&1, it = bid>>3;
  const int i0 = it*16, jsb = js*512;

  *(f32x4*)(smem + tid*80 + 32) = zero4();
  *(f32x4*)(smem + tid*80 + 48) = zero4();

  bf16x8 qf[2][2];
  #pragma unroll
  for (int hh=0; hh<2; ++hh){
    const unsigned short* qb = q + ((size_t)(b*16+2*w+hh)*2048 + i0 + lp)*64;
    qf[hh][0] = *(const bf16x8*)(qb + lg*8);
    qf[hh][1] = *(const bf16x8*)(qb + 32 + lg*8);
  }
  bf16x8 preB = zerob();
  if (lg < 2) preB = *(const bf16x8*)&wpre_t[lp*16 + lg*8];
  const float bpre_g = bpre[lp];

  float m[2], s[2];
  m[0] = -3.0e38f; m[1] = -3.0e38f; s[0] = 0.f; s[1] = 0.f;
  const size_t kbase0 = (size_t)(b*16 + 2*w)*131072;
  const size_t kbase1 = (size_t)(b*16 + 2*w+1)*131072;

  __syncthreads();

  for (int t=0; t<16; ++t){
    const int j0 = jsb + t*32;
    f32x4 s0[2], s1[2];
    #pragma unroll
    for (int jf=0;jf<2;++jf){ s0[jf]=zero4(); s1[jf]=zero4(); }
    #pragma unroll
    for (int kf=0; kf<2; ++kf){
      #pragma unroll
      for (int jf=0; jf<2; ++jf){
        size_t off = (size_t)(j0 + jf*16 + lp)*64 + kf*32 + lg*8;
        bf16x8 k0 = *(const bf16x8*)(kk + kbase0 + off);
        bf16x8 k1 = *(const bf16x8*)(kk + kbase1 + off);
        s0[jf] = mfma16(qf[0][kf], k0, s0[jf]);
        s1[jf] = mfma16(qf[1][kf], k1, s1[jf]);
      }
    }
    #pragma unroll
    for (int jf=0;jf<2;++jf)
      #pragma unroll
      for (int r=0;r<4;++r){
        int ij = (lg*4+r)*32 + jf*16 + lp;
        unsigned int pk = (unsigned int)f2bf(s0[jf][r]) | ((unsigned int)f2bf(s1[jf][r])<<16);
        *(unsigned int*)(smem + ij*80 + w*4) = pk;
      }
    __syncthreads();

    unsigned int mku0 = *(const unsigned int*)(mask + b*2048 + j0 + lg*4);
    unsigned int mku1 = *(const unsigned int*)(mask + b*2048 + j0 + 16 + lg*4);
    #pragma unroll
    for (int cc=0; cc<4; ++cc){
      int c = w*4+cc;
      bf16x8 afr = *(const bf16x8*)(smem + (c*16+lp)*80 + lg*16);
      f32x4 pa = mfma16(afr, preB, zero4());
      int il = 2*w + (cc>>1);
      int jl = (cc&1)*16 + lg*4;
      float4 pb = *(const float4*)&pos_bias[((size_t)lp*2048 + (i0+il))*2048 + j0 + jl];
      unsigned int mku = (cc&1) ? mku1 : mku0;
      float va0 = pa[0] + pb.x + bpre_g + (((mku    )&255u) ? -1e30f : 0.f);
      float va1 = pa[1] + pb.y + bpre_g + (((mku>> 8)&255u) ? -1e30f : 0.f);
      float va2 = pa[2] + pb.z + bpre_g + (((mku>>16)&255u) ? -1e30f : 0.f);
      float va3 = pa[3] + pb.w + bpre_g + (((mku>>24)&255u) ? -1e30f : 0.f);
      int ii = cc>>1;
      float vm = fmaxf(fmaxf(va0,va1), fmaxf(va2,va3));
      float nm = fmaxf(m[ii], vm);
      s[ii] = s[ii]*__expf(m[ii]-nm) + __expf(va0-nm)+__expf(va1-nm)+__expf(va2-nm)+__expf(va3-nm);
      m[ii] = nm;
    }
    __syncthreads();
  }

  #pragma unroll
  for (int ii=0; ii<2; ++ii){
    #pragma unroll
    for (int mk_=16; mk_<=32; mk_<<=1){
      float m2 = __shfl_xor(m[ii], mk_);
      float l2 = __shfl_xor(s[ii], mk_);
      float nm = fmaxf(m[ii], m2);
      s[ii] = s[ii]*__expf(m[ii]-nm) + l2*__expf(m2-nm);
      m[ii] = nm;
    }
  }
  if (lg == 0){
    int pidx = ((b*128+it)*4 + js)*256;
    #pragma unroll
    for (int ii=0; ii<2; ++ii){
      part_m[pidx + (2*w+ii)*16 + lp] = m[ii];
      part_l[pidx + (2*w+ii)*16 + lp] = s[ii];
    }
  }
}

__global__ __launch_bounds__(512,4) void k_pass2f(
    const unsigned short* __restrict__ q,
    const unsigned short* __restrict__ kk,
    const unsigned short* __restrict__ vt,
    const float* __restrict__ pos_bias,
    const unsigned char* __restrict__ mask,
    const unsigned short* __restrict__ wpre_t,
    const unsigned short* __restrict__ wpost_b,
    const float* __restrict__ bpre,
    const float* __restrict__ bpost,
    const float* __restrict__ vsum,
    const float* __restrict__ part_m,
    const float* __restrict__ part_l,
    float* __restrict__ pout0,
    float* __restrict__ pout1)
{
  __shared__ __align__(16) char smem[61440];
  const int tid = threadIdx.x;
  const int w = tid>>6, lane = tid&63, lg = lane>>4, lp = lane&15;
  const int bid = blockIdx.x;
  const int js = bid & 1, b = (bid>>1)&1, it = bid>>2;
  const int i0 = it*16, jsb = js*1024;

  *(f32x4*)(smem + tid*80 + 32) = zero4();
  *(f32x4*)(smem + tid*80 + 48) = zero4();

  bf16x8 qf[2][2];
  #pragma unroll
  for (int hh=0; hh<2; ++hh){
    const unsigned short* qb = q + ((size_t)(b*16+2*w+hh)*2048 + i0 + lp)*64;
    qf[hh][0] = *(const bf16x8*)(qb + lg*8);
    qf[hh][1] = *(const bf16x8*)(qb + 32 + lg*8);
  }
  bf16x8 preB = zerob(), postB = zerob();
  if (lg < 2){
    preB  = *(const bf16x8*)&wpre_t[lp*16 + lg*8];
    postB = *(const bf16x8*)&wpost_b[lp*16 + lg*8];
  }
  const float bpre_g = bpre[lp];

  float mC[2], linvC[2];
  {
    float lC[2]; mC[0]=mC[1]=-3.0e38f; lC[0]=lC[1]=0.f;
    int base = ((b*128+it)*4)*256;
    #pragma unroll
    for (int sj=0; sj<4; ++sj){
      #pragma unroll
      for (int ii=0; ii<2; ++ii){
        float mp  = part_m[base + sj*256 + (2*w+ii)*16 + lp];
        float lpv = part_l[base + sj*256 + (2*w+ii)*16 + lp];
        float nm = fmaxf(mC[ii], mp);
        lC[ii] = lC[ii]*__expf(mC[ii]-nm) + lpv*__expf(mp-nm);
        mC[ii] = nm;
      }
    }
    linvC[0] = 1.f/lC[0]; linvC[1] = 1.f/lC[1];
  }

  f32x4 oacc[2][4];
  #pragma unroll
  for (int hh=0; hh<2; ++hh)
    #pragma unroll
    for (int df=0; df<4; ++df) oacc[hh][df] = zero4();

  const size_t kbase0 = (size_t)(b*16 + 2*w)*131072;
  const size_t kbase1 = (size_t)(b*16 + 2*w+1)*131072;

  __syncthreads();

  for (int t=0; t<32; ++t){
    const int j0 = jsb + t*32;
    f32x4 s0[2], s1[2];
    #pragma unroll
    for (int jf=0;jf<2;++jf){ s0[jf]=zero4(); s1[jf]=zero4(); }
    #pragma unroll
    for (int kf=0; kf<2; ++kf){
      #pragma unroll
      for (int jf=0; jf<2; ++jf){
        size_t off = (size_t)(j0 + jf*16 + lp)*64 + kf*32 + lg*8;
        bf16x8 k0 = *(const bf16x8*)(kk + kbase0 + off);
        bf16x8 k1 = *(const bf16x8*)(kk + kbase1 + off);
        s0[jf] = mfma16(qf[0][kf], k0, s0[jf]);
        s1[jf] = mfma16(qf[1][kf], k1, s1[jf]);
      }
    }
    #pragma unroll
    for (int jf=0;jf<2;++jf)
      #pragma unroll
      for (int r=0;r<4;++r){
        int ij = (lg*4+r)*32 + jf*16 + lp;
        unsigned int pk = (unsigned int)f2bf(s0[jf][r]) | ((unsigned int)f2bf(s1[jf][r])<<16);
        *(unsigned int*)(smem + ij*80 + w*4) = pk;
      }
    __syncthreads();

    unsigned int mku0 = *(const unsigned int*)(mask + b*2048 + j0 + lg*4);
    unsigned int mku1 = *(const unsigned int*)(mask + b*2048 + j0 + 16 + lg*4);
    #pragma unroll
    for (int cc=0; cc<4; ++cc){
      int c = w*4+cc;
      bf16x8 afr = *(const bf16x8*)(smem + (c*16+lp)*80 + lg*16);
      f32x4 pa = mfma16(afr, preB, zero4());
      int il = 2*w + (cc>>1);
      int jl = (cc&1)*16 + lg*4;
      float4 pb = *(const float4*)&pos_bias[((size_t)lp*2048 + (i0+il))*2048 + j0 + jl];
      unsigned int mku = (cc&1) ? mku1 : mku0;
      float va0 = pa[0] + pb.x + bpre_g + (((mku    )&255u) ? -1e30f : 0.f);
      float va1 = pa[1] + pb.y + bpre_g + (((mku>> 8)&255u) ? -1e30f : 0.f);
      float va2 = pa[2] + pb.z + bpre_g + (((mku>>16)&255u) ? -1e30f : 0.f);
      float va3 = pa[3] + pb.w + bpre_g + (((mku>>24)&255u) ? -1e30f : 0.f);
      int ii = cc>>1;
      int rowb = (c*16 + lg*4);
      *(unsigned short*)(smem + (rowb+0)*80 + lp*2) = f2bf(__expf(va0-mC[ii])*linvC[ii]);
      *(unsigned short*)(smem + (rowb+1)*80 + lp*2) = f2bf(__expf(va1-mC[ii])*linvC[ii]);
      *(unsigned short*)(smem + (rowb+2)*80 + lp*2) = f2bf(__expf(va2-mC[ii])*linvC[ii]);
      *(unsigned short*)(smem + (rowb+3)*80 + lp*2) = f2bf(__expf(va3-mC[ii])*linvC[ii]);
    }
    __syncthreads();

    #pragma unroll
    for (int cc=0; cc<4; ++cc){
      int c = w*4+cc;
      bf16x8 a2 = *(const bf16x8*)(smem + (c*16+lp)*80 + lg*16);
      f32x4 aa = mfma16(a2, postB, zero4());
      int il = 2*w + (cc>>1);
      int jl = (cc&1)*16 + lg*4;
      short4v av;
      av.x = (short)f2bf(aa[0]); av.y = (short)f2bf(aa[1]);
      av.z = (short)f2bf(aa[2]); av.w = (short)f2bf(aa[3]);
      *(short4v*)(smem + 40960 + (lp*16 + il)*80 + jl*2) = av;
    }
    __syncthreads();

    #pragma unroll
    for (int hh=0; hh<2; ++hh){
      int gg = 2*w+hh;
      bf16x8 af = *(const bf16x8*)(smem + 40960 + (gg*16+lp)*80 + lg*16);
      #pragma unroll
      for (int df=0; df<4; ++df){
        bf16x8 vf = *(const bf16x8*)(vt + ((size_t)(b*16+gg)*64 + df*16 + lp)*2048 + j0 + lg*8);
        oacc[hh][df] = mfma16(af, vf, oacc[hh][df]);
      }
    }
    __syncthreads();
  }

  float* po = js ? pout1 : pout0;
  #pragma unroll
  for (int hh=0; hh<2; ++hh){
    int gg = 2*w+hh;
    float bp = (js==0) ? bpost[gg] : 0.f;
    #pragma unroll
    for (int df=0; df<4; ++df){
      int d = df*16+lp;
      float vs = vsum[(b*16+gg)*64 + d];
      #pragma unroll
      for (int r=0;r<4;++r){
        po[((size_t)b*2048 + i0 + lg*4 + r)*1024 + gg*64 + d] = oacc[hh][df][r] + bp*vs;
      }
    }
  }
}

// ======================================================================
extern "C" void kernel_launch(void* const* d_in, const int* in_sizes, int n_in,
                              void* d_out, int out_size, void* d_ws, size_t ws_size,
                              hipStream_t stream)
{
  const float* x        = (const float*)d_in[0];
  const float* pos_bias = (const float*)d_in[1];
  const unsigned char* mask = (const unsigned char*)d_in[2];
  const float* Wqkv     = (const float*)d_in[3];
  const float* Wout     = (const float*)d_in[4];
  const float* Wpre     = (const float*)d_in[5];
  const float* bpre     = (const float*)d_in[6];
  const float* Wpost    = (const float*)d_in[7];
  const float* bpost    = (const float*)d_in[8];
  const float* temp     = (const float*)d_in[9];
  float* out = (float*)d_out;
  float* kv_out = out + 4194304;

  char* ws = (char*)d_ws;
  unsigned short* XB    = (unsigned short*)(ws + 0);
  unsigned short* WT    = (unsigned short*)(ws + 8388608);
  unsigned short* WOT   = (unsigned short*)(ws + 8388608);
  float*          PART_M= (float*)        (ws + 10485760);
  float*          PART_L= (float*)        (ws + 11534336);
  unsigned short* WPRE  = (unsigned short*)(ws + 12582912);
  unsigned short* WPRE2 = (unsigned short*)(ws + 12583424);
  unsigned short* WPOST = (unsigned short*)(ws + 12583936);
  float*          VSUM  = (float*)        (ws + 12584448);
  float*          MASKF = (float*)        (ws + 12593152);
  unsigned short* QKV   = (unsigned short*)(ws + 14680064);
  unsigned short* VT    = (unsigned short*)(ws + 14680064);
  float*          POUT0 = (float*)        (ws + 23068672);
  unsigned short* Q     = (unsigned short*)(ws + 39845888);
  unsigned short* KB    = (unsigned short*)(ws + 48234496);
  unsigned short* VB    = (unsigned short*)(ws + 56623104);
  float*          POUT1 = (float*)        (ws + 56623104);
  unsigned short* PB    = (unsigned short*)(ws + 75497472);   // 268.4 MB (new path only)
  unsigned short* AO    = XB;

  const int use_new = (ws_size >= (size_t)343932928);

  k_f32_to_bf16<<<4096, 256, 0, stream>>>(x, XB, 1048576);
  k_convT<<<dim3(96,32), 256, 0, stream>>>(Wqkv, WT, 1024, 3072);
  k_gemm<0><<<dim3(24,32), 256, 0, stream>>>(XB, WT, (void*)QKV, 4096, 3072, 1024);
  k_split_norm<<<16384, 256, 0, stream>>>(QKV, Q, KB, VB, kv_out);
  k_transpose_v<<<dim3(32,32), 256, 0, stream>>>(VB, VT);
  k_vsum<<<32, 256, 0, stream>>>(VB, VSUM);
  k_prep<<<1, 256, 0, stream>>>(Wpre, Wpost, temp, WPRE, WPRE2, WPOST);
  k_maskf<<<16, 256, 0, stream>>>(mask, MASKF);
  k_convT<<<dim3(32,32), 256, 0, stream>>>(Wout, WOT, 1024, 1024);

  if (use_new){
    k_score<<<1024, 512, 0, stream>>>(Q, KB, pos_bias, MASKF, WPRE2, bpre, PB, PART_L);
    k_mix<<<512, 512, 0, stream>>>(PB, VT, WPOST, bpost, VSUM, PART_L, POUT0, POUT1);
  } else {
    k_pass1f<<<1024, 512, 0, stream>>>(Q, KB, pos_bias, mask, WPRE, bpre, PART_M, PART_L);
    k_pass2f<<<512, 512, 0, stream>>>(Q, KB, VT, pos_bias, mask, WPRE, WPOST, bpre, bpost, VSUM,
                                      PART_M, PART_L, POUT0, POUT1);
  }
  k_combine<<<4096, 256, 0, stream>>>(POUT0, POUT1, AO);
  k_gemm<1><<<dim3(8,32), 256, 0, stream>>>(AO, WOT, d_out, 4096, 1024, 1024);
}

// Round 7
// 862.729 us; speedup vs baseline: 1.0767x; 1.0767x over previous
//
#include <hip/hip_runtime.h>
#include <stdint.h>

typedef __attribute__((ext_vector_type(8))) short bf16x8;
typedef __attribute__((ext_vector_type(4))) float f32x4;
typedef __attribute__((ext_vector_type(4))) short short4v;

#define DEV __device__ __forceinline__
#define L2E 1.4426950408889634f

DEV float bf2f(unsigned short s){ union{unsigned int u; float f;} x; x.u = ((unsigned int)s)<<16; return x.f; }
DEV unsigned short f2bf(float f){ union{float f; unsigned int u;} x; x.f = f; x.u += 0x7fffu + ((x.u>>16)&1u); return (unsigned short)(x.u>>16); }

DEV f32x4 mfma16(bf16x8 a, bf16x8 b, f32x4 c){
  return __builtin_amdgcn_mfma_f32_16x16x32_bf16(a, b, c, 0, 0, 0);
}
DEV f32x4 zero4(){ f32x4 z; z[0]=0.f; z[1]=0.f; z[2]=0.f; z[3]=0.f; return z; }
DEV bf16x8 zerob(){ bf16x8 z; z[0]=0;z[1]=0;z[2]=0;z[3]=0;z[4]=0;z[5]=0;z[6]=0;z[7]=0; return z; }
DEV float fexp2(float x){ float r; asm volatile("v_exp_f32 %0, %1" : "=v"(r) : "v"(x)); return r; }
DEV void barw(){ asm volatile("s_waitcnt lgkmcnt(0)" ::: "memory"); __builtin_amdgcn_s_barrier(); }

// ---------------- elementwise f32 -> bf16 ----------------
__global__ __launch_bounds__(256) void k_f32_to_bf16(const float* __restrict__ in, unsigned short* __restrict__ out, int n4){
  int i = blockIdx.x*256 + threadIdx.x;
  if (i < n4){
    float4 v = ((const float4*)in)[i];
    short4v o; o.x=(short)f2bf(v.x); o.y=(short)f2bf(v.y); o.z=(short)f2bf(v.z); o.w=(short)f2bf(v.w);
    ((short4v*)out)[i] = o;
  }
}

// ------------- f32 [R][C] -> bf16 transposed [C][R] -------------
__global__ __launch_bounds__(256) void k_convT(const float* __restrict__ in, unsigned short* __restrict__ out, int R, int Cc){
  __shared__ float t[32][33];
  int c0 = blockIdx.x*32, r0 = blockIdx.y*32;
  int tid = threadIdx.x;
  int row = tid>>3, col4 = (tid&7)*4;
  float4 v = *(const float4*)&in[(size_t)(r0+row)*Cc + c0 + col4];
  t[row][col4+0]=v.x; t[row][col4+1]=v.y; t[row][col4+2]=v.z; t[row][col4+3]=v.w;
  __syncthreads();
  short4v o;
  o.x=(short)f2bf(t[col4+0][row]); o.y=(short)f2bf(t[col4+1][row]);
  o.z=(short)f2bf(t[col4+2][row]); o.w=(short)f2bf(t[col4+3][row]);
  *(short4v*)&out[(size_t)(c0+row)*R + r0 + col4] = o;
}

// ------------- small prep -------------
__global__ __launch_bounds__(256) void k_prep(const float* __restrict__ wpre, const float* __restrict__ wpost,
                                              const float* __restrict__ temp,
                                              unsigned short* __restrict__ wpre_t,
                                              unsigned short* __restrict__ wpre_t2,
                                              unsigned short* __restrict__ wpost_b){
  int t = threadIdx.x;
  float T = temp[0];
  wpre_t[t]  = f2bf(wpre[t]*T);
  wpre_t2[t] = f2bf(wpre[t]*T*L2E);
  wpost_b[t] = f2bf(wpost[t]);
}

// ------------- mask bytes -> f32 addend -------------
__global__ __launch_bounds__(256) void k_maskf(const unsigned char* __restrict__ mask, float* __restrict__ maskf){
  int i = blockIdx.x*256 + threadIdx.x;
  if (i < 4096) maskf[i] = mask[i] ? -1e30f : 0.f;
}

// ------------- GEMM -------------
template<int OUTF>
__global__ __launch_bounds__(256,2) void k_gemm(const unsigned short* __restrict__ A, const unsigned short* __restrict__ Bt,
                                                void* __restrict__ Cv, int M, int Nn, int K){
  __shared__ unsigned short As[128][72];
  __shared__ unsigned short Bs[128][72];
  int tid = threadIdx.x;
  int n0 = blockIdx.x*128, m0 = blockIdx.y*128;
  int w = tid>>6, lane = tid&63, lg = lane>>4, lp = lane&15;
  int wm = (w>>1)*64, wn = (w&1)*64;
  f32x4 acc[4][4];
  #pragma unroll
  for (int i=0;i<4;++i)
    #pragma unroll
    for (int j=0;j<4;++j) acc[i][j] = zero4();

  for (int kt=0; kt<K; kt+=64){
    #pragma unroll
    for (int cch=0; cch<4; ++cch){
      int e = tid + cch*256; int r = e>>3, cl = (e&7)*8;
      *(bf16x8*)&As[r][cl] = *(const bf16x8*)&A[(size_t)(m0+r)*K + kt + cl];
      *(bf16x8*)&Bs[r][cl] = *(const bf16x8*)&Bt[(size_t)(n0+r)*K + kt + cl];
    }
    __syncthreads();
    #pragma unroll
    for (int ks=0; ks<2; ++ks){
      bf16x8 a[4], b[4];
      #pragma unroll
      for (int mi=0; mi<4; ++mi) a[mi] = *(const bf16x8*)&As[wm+mi*16+lp][ks*32 + lg*8];
      #pragma unroll
      for (int ni=0; ni<4; ++ni) b[ni] = *(const bf16x8*)&Bs[wn+ni*16+lp][ks*32 + lg*8];
      #pragma unroll
      for (int mi=0; mi<4; ++mi)
        #pragma unroll
        for (int ni=0; ni<4; ++ni)
          acc[mi][ni] = mfma16(a[mi], b[ni], acc[mi][ni]);
    }
    __syncthreads();
  }
  #pragma unroll
  for (int mi=0; mi<4; ++mi)
    #pragma unroll
    for (int ni=0; ni<4; ++ni)
      #pragma unroll
      for (int r=0; r<4; ++r){
        int row = m0+wm+mi*16+lg*4+r, col = n0+wn+ni*16+lp;
        if (OUTF) ((float*)Cv)[(size_t)row*Nn+col] = acc[mi][ni][r];
        else ((unsigned short*)Cv)[(size_t)row*Nn+col] = f2bf(acc[mi][ni][r]);
      }
}

// ------------- split qkv, l2norm q/k -------------
__global__ __launch_bounds__(256) void k_split_norm(const unsigned short* __restrict__ qkv,
                                                    unsigned short* __restrict__ q, unsigned short* __restrict__ k,
                                                    unsigned short* __restrict__ v, float* __restrict__ kv_out){
  int w = threadIdx.x>>6, lane = threadIdx.x&63;
  int widx = blockIdx.x*4 + w;
  int h = widx & 15; int bn = widx >> 4;
  int b = bn >> 11; int n = bn & 2047;
  size_t base = (size_t)bn*3072 + h*192 + lane*3;
  float qv = bf2f(qkv[base]), kvv = bf2f(qkv[base+1]), vv = bf2f(qkv[base+2]);
  float nq = qv*qv, nk = kvv*kvv;
  #pragma unroll
  for (int m=1; m<64; m<<=1){ nq += __shfl_xor(nq, m); nk += __shfl_xor(nk, m); }
  float qn = qv / fmaxf(sqrtf(nq), 1e-12f);
  float kn = kvv / fmaxf(sqrtf(nk), 1e-12f);
  size_t idx = ((size_t)(b*16+h)*2048 + n)*64 + lane;
  q[idx] = f2bf(qn); k[idx] = f2bf(kn); v[idx] = f2bf(vv);
  kv_out[idx] = kn;
  kv_out[4194304 + idx] = vv;
}

// ------------- v -> vt transposed -------------
__global__ __launch_bounds__(256) void k_transpose_v(const unsigned short* __restrict__ v, unsigned short* __restrict__ vt){
  __shared__ unsigned short t[64][72];
  int bh = blockIdx.y; int n0 = blockIdx.x*64;
  int tid = threadIdx.x;
  #pragma unroll
  for (int cch=0; cch<2; ++cch){
    int e = tid + cch*256; int r = e>>3, c8 = (e&7)*8;
    *(bf16x8*)&t[r][c8] = *(const bf16x8*)&v[((size_t)bh*2048 + n0 + r)*64 + c8];
  }
  __syncthreads();
  #pragma unroll
  for (int cch=0; cch<2; ++cch){
    int e = tid + cch*256; int d = e>>3, nn8 = (e&7)*8;
    bf16x8 o;
    #pragma unroll
    for (int i=0;i<8;++i) o[i] = (short)t[nn8+i][d];
    *(bf16x8*)&vt[((size_t)bh*64 + d)*2048 + n0 + nn8] = o;
  }
}

// ------------- vsum -------------
__global__ __launch_bounds__(256) void k_vsum(const unsigned short* __restrict__ v, float* __restrict__ vsum){
  int bg = blockIdx.x;
  int d = threadIdx.x & 63, part = threadIdx.x>>6;
  float s = 0.f;
  for (int n = part*512; n < part*512+512; ++n) s += bf2f(v[((size_t)bg*2048 + n)*64 + d]);
  __shared__ float red[4][64];
  red[part][d] = s; __syncthreads();
  if (part==0) vsum[bg*64 + d] = red[0][d]+red[1][d]+red[2][d]+red[3][d];
}

// =================================================================
// k_score tile body — real function, named prefetch buffers (no macros)
// =================================================================
DEV void score_tile(
    int j0, int j0n, char* sbuf,
    const unsigned short* __restrict__ kk, size_t kbase0, size_t kbase1,
    const float* __restrict__ pos_bias, const float* __restrict__ maskf, int mbase,
    const bf16x8 (&qf)[2][2], bf16x8 preA, const float (&bpre_s)[4],
    bf16x8 (&k0v)[4], bf16x8 (&k1v)[4],
    float (&PBC)[4][4], float (&PBN)[4][4],
    float (&sacc)[2][4],
    unsigned short* __restrict__ Pb, int b, int i0,
    int w, int lg, int lp)
{
  // 1. issue next-tile pos_bias loads (consumed next tile -> ~1 tile cover)
  #pragma unroll
  for (int cc=0; cc<4; ++cc){
    int il = 2*w + (cc>>1);
    int jl = (cc&1)*16 + lp;
    #pragma unroll
    for (int r=0;r<4;++r)
      PBN[cc][r] = pos_bias[(size_t)(lg*4+r)*4194304 + (size_t)(i0+il)*2048 + j0n + jl];
  }
  // 2. QK MFMA (K prefetched last tile)
  f32x4 s0[2], s1[2];
  #pragma unroll
  for (int jf=0;jf<2;++jf){ s0[jf]=zero4(); s1[jf]=zero4(); }
  #pragma unroll
  for (int kf=0; kf<2; ++kf)
    #pragma unroll
    for (int jf=0; jf<2; ++jf){
      s0[jf] = mfma16(qf[0][kf], k0v[kf*2+jf], s0[jf]);
      s1[jf] = mfma16(qf[1][kf], k1v[kf*2+jf], s1[jf]);
    }
  // 3. S write (40B rows, XOR-16B swizzle on dword col)
  #pragma unroll
  for (int jf=0;jf<2;++jf)
    #pragma unroll
    for (int r=0;r<4;++r){
      int ij = (lg*4+r)*32 + jf*16 + lp;
      unsigned int pk = (unsigned int)f2bf(s0[jf][r]) | ((unsigned int)f2bf(s1[jf][r])<<16);
      int col = w ^ (((ij>>7)&1)<<2);
      *(unsigned int*)(sbuf + ij*40 + col*4) = pk;
    }
  // 4. K prefetch for next tile
  #pragma unroll
  for (int kf=0; kf<2; ++kf)
    #pragma unroll
    for (int jf=0; jf<2; ++jf){
      size_t off = (size_t)(j0n + jf*16 + lp)*64 + kf*32 + lg*8;
      k0v[kf*2+jf] = *(const bf16x8*)(kk + kbase0 + off);
      k1v[kf*2+jf] = *(const bf16x8*)(kk + kbase1 + off);
    }
  // 5. mask (L2-resident)
  float mk0 = maskf[mbase + j0 + lp];
  float mk1 = maskf[mbase + j0 + 16 + lp];
  // 6. one barrier
  barw();
  // 7. premix + exp2 + Pb store (consumes PBC issued one tile ago)
  #pragma unroll
  for (int cc=0; cc<4; ++cc){
    int c = w*4+cc;
    int il = 2*w + (cc>>1);
    int jl = (cc&1)*16 + lp;
    bf16x8 sfrag = zerob();
    if (lg < 2) sfrag = *(const bf16x8*)(sbuf + (c*16+lp)*40 + ((lg ^ ((c>>3)&1))<<4));
    f32x4 pa = mfma16(preA, sfrag, zero4());
    float mkj = (cc&1) ? mk1 : mk0;
    float pv0 = fexp2(fmaf(PBC[cc][0], L2E, pa[0] + bpre_s[0] + mkj));
    float pv1 = fexp2(fmaf(PBC[cc][1], L2E, pa[1] + bpre_s[1] + mkj));
    float pv2 = fexp2(fmaf(PBC[cc][2], L2E, pa[2] + bpre_s[2] + mkj));
    float pv3 = fexp2(fmaf(PBC[cc][3], L2E, pa[3] + bpre_s[3] + mkj));
    sacc[cc>>1][0] += pv0; sacc[cc>>1][1] += pv1;
    sacc[cc>>1][2] += pv2; sacc[cc>>1][3] += pv3;
    short4v p4;
    p4.x = (short)f2bf(pv0); p4.y = (short)f2bf(pv1);
    p4.z = (short)f2bf(pv2); p4.w = (short)f2bf(pv3);
    *(short4v*)&Pb[(((size_t)(b*2048 + i0+il)*2048) + j0 + jl)*16 + lg*4] = p4;
  }
}

// grid 1024: bid -> (b, it, js4). LDS = 2 x 20KB S buffers.
__global__ __launch_bounds__(512,4) void k_score(
    const unsigned short* __restrict__ q,
    const unsigned short* __restrict__ kk,
    const float* __restrict__ pos_bias,
    const float* __restrict__ maskf,
    const unsigned short* __restrict__ wpre_t2,
    const float* __restrict__ bpre,
    unsigned short* __restrict__ Pb,
    float* __restrict__ part_l)
{
  __shared__ __align__(16) char smem[40960];
  const int tid = threadIdx.x;
  const int w = tid>>6, lane = tid&63, lg = lane>>4, lp = lane&15;
  const int bid = blockIdx.x;
  const int qd = bid>>4, r2 = bid&15;
  const int b = r2>>3, n = qd*8 + (r2&7);
  const int it = n>>2, js = n&3;
  const int i0 = it*16, jsb = js*512;
  const int mbase = b*2048;

  bf16x8 qf[2][2];
  #pragma unroll
  for (int hh=0; hh<2; ++hh){
    const unsigned short* qb = q + ((size_t)(b*16+2*w+hh)*2048 + i0 + lp)*64;
    qf[hh][0] = *(const bf16x8*)(qb + lg*8);
    qf[hh][1] = *(const bf16x8*)(qb + 32 + lg*8);
  }
  bf16x8 preA = zerob();
  if (lg < 2) preA = *(const bf16x8*)&wpre_t2[lp*16 + lg*8];
  float bpre_s[4];
  #pragma unroll
  for (int r=0;r<4;++r) bpre_s[r] = bpre[lg*4+r]*L2E - 32.0f;

  float sacc[2][4];
  #pragma unroll
  for (int ii=0;ii<2;++ii)
    #pragma unroll
    for (int r=0;r<4;++r) sacc[ii][r] = 0.f;

  const size_t kbase0 = (size_t)(b*16 + 2*w)*131072;
  const size_t kbase1 = (size_t)(b*16 + 2*w+1)*131072;

  // prefetch K(0) and pb(0)
  bf16x8 k0v[4], k1v[4];
  #pragma unroll
  for (int kf=0; kf<2; ++kf)
    #pragma unroll
    for (int jf=0; jf<2; ++jf){
      size_t off = (size_t)(jsb + jf*16 + lp)*64 + kf*32 + lg*8;
      k0v[kf*2+jf] = *(const bf16x8*)(kk + kbase0 + off);
      k1v[kf*2+jf] = *(const bf16x8*)(kk + kbase1 + off);
    }
  float pbA[4][4], pbB[4][4];
  #pragma unroll
  for (int cc=0; cc<4; ++cc){
    int il = 2*w + (cc>>1);
    int jl = (cc&1)*16 + lp;
    #pragma unroll
    for (int r=0;r<4;++r)
      pbA[cc][r] = pos_bias[(size_t)(lg*4+r)*4194304 + (size_t)(i0+il)*2048 + jsb + jl];
  }

  for (int tt=0; tt<8; ++tt){
    int t0 = 2*tt, t1 = 2*tt+1;
    score_tile(jsb + t0*32, jsb + ((t0+1)&15)*32, smem + (t0&1)*20480,
               kk, kbase0, kbase1, pos_bias, maskf, mbase,
               qf, preA, bpre_s, k0v, k1v, pbA, pbB, sacc, Pb, b, i0, w, lg, lp);
    score_tile(jsb + t1*32, jsb + ((t1+1)&15)*32, smem + (t1&1)*20480,
               kk, kbase0, kbase1, pos_bias, maskf, mbase,
               qf, preA, bpre_s, k0v, k1v, pbB, pbA, sacc, Pb, b, i0, w, lg, lp);
  }

  #pragma unroll
  for (int ii=0;ii<2;++ii)
    #pragma unroll
    for (int r=0;r<4;++r){
      float v = sacc[ii][r];
      #pragma unroll
      for (int m=1; m<16; m<<=1) v += __shfl_xor(v, m);
      sacc[ii][r] = v;
    }
  if (lp == 0){
    int base = ((b*128+it)*4 + js)*256;
    #pragma unroll
    for (int ii=0;ii<2;++ii){
      float4 st; st.x = sacc[ii][0]; st.y = sacc[ii][1]; st.z = sacc[ii][2]; st.w = sacc[ii][3];
      *(float4*)&part_l[base + (2*w+ii)*16 + lg*4] = st;
    }
  }
}

// =================================================================
// k_mix tile body — real function, named prefetch buffers
// =================================================================
DEV void mix_tile(
    int j0, int j0n, char* abuf,
    const unsigned short* __restrict__ Pb,
    const unsigned short* __restrict__ vt,
    const bf16x8 (&postB)[2],
    bf16x8 (&PC)[4], bf16x8 (&PN)[4],
    f32x4 (&oacc)[2][4],
    int b, int i0, int w, int lg, int lp)
{
  // 1. issue next-tile Pb loads
  #pragma unroll
  for (int cc=0; cc<4; ++cc){
    int il = 2*w + (cc>>1);
    PN[cc] = zerob();
    if (lg < 2)
      PN[cc] = *(const bf16x8*)&Pb[(((size_t)(b*2048 + i0+il)*2048) + j0n + (cc&1)*16 + lp)*16 + lg*8];
  }
  // 2. V loads for this tile (consumed after barrier)
  bf16x8 vfr[2][4];
  #pragma unroll
  for (int hh=0; hh<2; ++hh)
    #pragma unroll
    for (int df=0; df<4; ++df)
      vfr[hh][df] = *(const bf16x8*)(vt + ((size_t)(b*16+2*w+hh)*64 + df*16 + lp)*2048 + j0 + lg*8);
  // 3. postmix -> Al (XOR-swizzled 8B chunks)
  #pragma unroll
  for (int cc=0; cc<4; ++cc){
    int il = 2*w + (cc>>1);
    f32x4 aa = mfma16(PC[cc], postB[cc>>1], zero4());
    short4v av;
    av.x = (short)f2bf(aa[0]); av.y = (short)f2bf(aa[1]);
    av.z = (short)f2bf(aa[2]); av.w = (short)f2bf(aa[3]);
    int row = lp*16 + il;
    int chunk = ((cc&1)*4 + lg) ^ ((lp ^ il)&6);
    *(short4v*)(abuf + row*64 + chunk*8) = av;
  }
  barw();
  // 4. PV
  #pragma unroll
  for (int hh=0; hh<2; ++hh){
    int gg = 2*w+hh;
    bf16x8 af = *(const bf16x8*)(abuf + (gg*16+lp)*64 + (((lg*2) ^ ((gg^lp)&6))*8));
    #pragma unroll
    for (int df=0; df<4; ++df)
      oacc[hh][df] = mfma16(af, vfr[hh][df], oacc[hh][df]);
  }
}

// grid 512: bid -> (b, it, js2). LDS = 2x16KB Al + 1KB linv.
__global__ __launch_bounds__(512,4) void k_mix(
    const unsigned short* __restrict__ Pb,
    const unsigned short* __restrict__ vt,
    const unsigned short* __restrict__ wpost_b,
    const float* __restrict__ bpost,
    const float* __restrict__ vsum,
    const float* __restrict__ part_l,
    float* __restrict__ pout0,
    float* __restrict__ pout1)
{
  __shared__ __align__(16) char smem[33792];
  float* linv = (float*)(smem + 32768);
  const int tid = threadIdx.x;
  const int w = tid>>6, lane = tid&63, lg = lane>>4, lp = lane&15;
  const int bid = blockIdx.x;
  const int qd = bid>>4, r2 = bid&15;
  const int b = r2>>3, n = qd*8 + (r2&7);
  const int it = n>>1, js = n&1;
  const int i0 = it*16, jsb = js*1024;

  if (tid < 256){
    int base = ((b*128+it)*4)*256 + tid;
    float sum = part_l[base] + part_l[base+256] + part_l[base+512] + part_l[base+768];
    linv[tid] = 1.f/sum;
  }
  __syncthreads();

  bf16x8 postB[2];
  #pragma unroll
  for (int ii=0;ii<2;++ii){
    postB[ii] = zerob();
    if (lg < 2){
      bf16x8 wf = *(const bf16x8*)&wpost_b[lp*16 + lg*8];
      int i = 2*w+ii;
      #pragma unroll
      for (int e=0;e<8;++e){
        float vsc = bf2f((unsigned short)wf[e]) * linv[i*16 + lg*8 + e];
        postB[ii][e] = (short)f2bf(vsc);
      }
    }
  }

  f32x4 oacc[2][4];
  #pragma unroll
  for (int hh=0; hh<2; ++hh)
    #pragma unroll
    for (int df=0; df<4; ++df) oacc[hh][df] = zero4();

  // prefetch Pb(0)
  bf16x8 pbC[4], pbN[4];
  #pragma unroll
  for (int cc=0; cc<4; ++cc){
    pbC[cc] = zerob();
    int il = 2*w + (cc>>1);
    if (lg < 2)
      pbC[cc] = *(const bf16x8*)&Pb[(((size_t)(b*2048 + i0+il)*2048) + jsb + (cc&1)*16 + lp)*16 + lg*8];
  }
  __syncthreads();

  for (int tt=0; tt<16; ++tt){
    int t0 = 2*tt, t1 = 2*tt+1;
    mix_tile(jsb + t0*32, jsb + ((t0+1)&31)*32, smem + (t0&1)*16384,
             Pb, vt, postB, pbC, pbN, oacc, b, i0, w, lg, lp);
    mix_tile(jsb + t1*32, jsb + ((t1+1)&31)*32, smem + (t1&1)*16384,
             Pb, vt, postB, pbN, pbC, oacc, b, i0, w, lg, lp);
  }

  float* po = js ? pout1 : pout0;
  #pragma unroll
  for (int hh=0; hh<2; ++hh){
    int gg = 2*w+hh;
    float bp = (js==0) ? bpost[gg] : 0.f;
    #pragma unroll
    for (int df=0; df<4; ++df){
      int d = df*16+lp;
      float vs = vsum[(b*16+gg)*64 + d];
      #pragma unroll
      for (int r=0;r<4;++r){
        po[((size_t)b*2048 + i0 + lg*4 + r)*1024 + gg*64 + d] = oacc[hh][df][r] + bp*vs;
      }
    }
  }
}

// ------------- combine partial outputs -> bf16 attn_out -------------
__global__ __launch_bounds__(256) void k_combine(const float* __restrict__ p0, const float* __restrict__ p1,
                                                 unsigned short* __restrict__ ao){
  int i = blockIdx.x*256 + threadIdx.x;
  float4 a = ((const float4*)p0)[i];
  float4 c = ((const float4*)p1)[i];
  short4v o;
  o.x=(short)f2bf(a.x+c.x); o.y=(short)f2bf(a.y+c.y);
  o.z=(short)f2bf(a.z+c.z); o.w=(short)f2bf(a.w+c.w);
  ((short4v*)ao)[i] = o;
}

// =================================================================
// OLD PATH (fallback for small ws): two-pass recompute
// =================================================================
__global__ __launch_bounds__(512,6) void k_pass1f(
    const unsigned short* __restrict__ q,
    const unsigned short* __restrict__ kk,
    const float* __restrict__ pos_bias,
    const unsigned char* __restrict__ mask,
    const unsigned short* __restrict__ wpre_t,
    const float* __restrict__ bpre,
    float* __restrict__ part_m,
    float* __restrict__ part_l)
{
  __shared__ __align__(16) char smem[40960];
  const int tid = threadIdx.x;
  const int w = tid>>6, lane = tid&63, lg = lane>>4, lp = lane&15;
  const int bid = blockIdx.x;
  const int js = bid & 3, b = (bid>>2)&1, it = bid>>3;
  const int i0 = it*16, jsb = js*512;

  *(f32x4*)(smem + tid*80 + 32) = zero4();
  *(f32x4*)(smem + tid*80 + 48) = zero4();

  bf16x8 qf[2][2];
  #pragma unroll
  for (int hh=0; hh<2; ++hh){
    const unsigned short* qb = q + ((size_t)(b*16+2*w+hh)*2048 + i0 + lp)*64;
    qf[hh][0] = *(const bf16x8*)(qb + lg*8);
    qf[hh][1] = *(const bf16x8*)(qb + 32 + lg*8);
  }
  bf16x8 preB = zerob();
  if (lg < 2) preB = *(const bf16x8*)&wpre_t[lp*16 + lg*8];
  const float bpre_g = bpre[lp];

  float m[2], s[2];
  m[0] = -3.0e38f; m[1] = -3.0e38f; s[0] = 0.f; s[1] = 0.f;
  const size_t kbase0 = (size_t)(b*16 + 2*w)*131072;
  const size_t kbase1 = (size_t)(b*16 + 2*w+1)*131072;

  __syncthreads();

  for (int t=0; t<16; ++t){
    const int j0 = jsb + t*32;
    f32x4 s0[2], s1[2];
    #pragma unroll
    for (int jf=0;jf<2;++jf){ s0[jf]=zero4(); s1[jf]=zero4(); }
    #pragma unroll
    for (int kf=0; kf<2; ++kf){
      #pragma unroll
      for (int jf=0; jf<2; ++jf){
        size_t off = (size_t)(j0 + jf*16 + lp)*64 + kf*32 + lg*8;
        bf16x8 k0 = *(const bf16x8*)(kk + kbase0 + off);
        bf16x8 k1 = *(const bf16x8*)(kk + kbase1 + off);
        s0[jf] = mfma16(qf[0][kf], k0, s0[jf]);
        s1[jf] = mfma16(qf[1][kf], k1, s1[jf]);
      }
    }
    #pragma unroll
    for (int jf=0;jf<2;++jf)
      #pragma unroll
      for (int r=0;r<4;++r){
        int ij = (lg*4+r)*32 + jf*16 + lp;
        unsigned int pk = (unsigned int)f2bf(s0[jf][r]) | ((unsigned int)f2bf(s1[jf][r])<<16);
        *(unsigned int*)(smem + ij*80 + w*4) = pk;
      }
    __syncthreads();

    unsigned int mku0 = *(const unsigned int*)(mask + b*2048 + j0 + lg*4);
    unsigned int mku1 = *(const unsigned int*)(mask + b*2048 + j0 + 16 + lg*4);
    #pragma unroll
    for (int cc=0; cc<4; ++cc){
      int c = w*4+cc;
      bf16x8 afr = *(const bf16x8*)(smem + (c*16+lp)*80 + lg*16);
      f32x4 pa = mfma16(afr, preB, zero4());
      int il = 2*w + (cc>>1);
      int jl = (cc&1)*16 + lg*4;
      float4 pb = *(const float4*)&pos_bias[((size_t)lp*2048 + (i0+il))*2048 + j0 + jl];
      unsigned int mku = (cc&1) ? mku1 : mku0;
      float va0 = pa[0] + pb.x + bpre_g + (((mku    )&255u) ? -1e30f : 0.f);
      float va1 = pa[1] + pb.y + bpre_g + (((mku>> 8)&255u) ? -1e30f : 0.f);
      float va2 = pa[2] + pb.z + bpre_g + (((mku>>16)&255u) ? -1e30f : 0.f);
      float va3 = pa[3] + pb.w + bpre_g + (((mku>>24)&255u) ? -1e30f : 0.f);
      int ii = cc>>1;
      float vm = fmaxf(fmaxf(va0,va1), fmaxf(va2,va3));
      float nm = fmaxf(m[ii], vm);
      s[ii] = s[ii]*__expf(m[ii]-nm) + __expf(va0-nm)+__expf(va1-nm)+__expf(va2-nm)+__expf(va3-nm);
      m[ii] = nm;
    }
    __syncthreads();
  }

  #pragma unroll
  for (int ii=0; ii<2; ++ii){
    #pragma unroll
    for (int mk_=16; mk_<=32; mk_<<=1){
      float m2 = __shfl_xor(m[ii], mk_);
      float l2 = __shfl_xor(s[ii], mk_);
      float nm = fmaxf(m[ii], m2);
      s[ii] = s[ii]*__expf(m[ii]-nm) + l2*__expf(m2-nm);
      m[ii] = nm;
    }
  }
  if (lg == 0){
    int pidx = ((b*128+it)*4 + js)*256;
    #pragma unroll
    for (int ii=0; ii<2; ++ii){
      part_m[pidx + (2*w+ii)*16 + lp] = m[ii];
      part_l[pidx + (2*w+ii)*16 + lp] = s[ii];
    }
  }
}

__global__ __launch_bounds__(512,4) void k_pass2f(
    const unsigned short* __restrict__ q,
    const unsigned short* __restrict__ kk,
    const unsigned short* __restrict__ vt,
    const float* __restrict__ pos_bias,
    const unsigned char* __restrict__ mask,
    const unsigned short* __restrict__ wpre_t,
    const unsigned short* __restrict__ wpost_b,
    const float* __restrict__ bpre,
    const float* __restrict__ bpost,
    const float* __restrict__ vsum,
    const float* __restrict__ part_m,
    const float* __restrict__ part_l,
    float* __restrict__ pout0,
    float* __restrict__ pout1)
{
  __shared__ __align__(16) char smem[61440];
  const int tid = threadIdx.x;
  const int w = tid>>6, lane = tid&63, lg = lane>>4, lp = lane&15;
  const int bid = blockIdx.x;
  const int js = bid & 1, b = (bid>>1)&1, it = bid>>2;
  const int i0 = it*16, jsb = js*1024;

  *(f32x4*)(smem + tid*80 + 32) = zero4();
  *(f32x4*)(smem + tid*80 + 48) = zero4();

  bf16x8 qf[2][2];
  #pragma unroll
  for (int hh=0; hh<2; ++hh){
    const unsigned short* qb = q + ((size_t)(b*16+2*w+hh)*2048 + i0 + lp)*64;
    qf[hh][0] = *(const bf16x8*)(qb + lg*8);
    qf[hh][1] = *(const bf16x8*)(qb + 32 + lg*8);
  }
  bf16x8 preB = zerob(), postB = zerob();
  if (lg < 2){
    preB  = *(const bf16x8*)&wpre_t[lp*16 + lg*8];
    postB = *(const bf16x8*)&wpost_b[lp*16 + lg*8];
  }
  const float bpre_g = bpre[lp];

  float mC[2], linvC[2];
  {
    float lC[2]; mC[0]=mC[1]=-3.0e38f; lC[0]=lC[1]=0.f;
    int base = ((b*128+it)*4)*256;
    #pragma unroll
    for (int sj=0; sj<4; ++sj){
      #pragma unroll
      for (int ii=0; ii<2; ++ii){
        float mp  = part_m[base + sj*256 + (2*w+ii)*16 + lp];
        float lpv = part_l[base + sj*256 + (2*w+ii)*16 + lp];
        float nm = fmaxf(mC[ii], mp);
        lC[ii] = lC[ii]*__expf(mC[ii]-nm) + lpv*__expf(mp-nm);
        mC[ii] = nm;
      }
    }
    linvC[0] = 1.f/lC[0]; linvC[1] = 1.f/lC[1];
  }

  f32x4 oacc[2][4];
  #pragma unroll
  for (int hh=0; hh<2; ++hh)
    #pragma unroll
    for (int df=0; df<4; ++df) oacc[hh][df] = zero4();

  const size_t kbase0 = (size_t)(b*16 + 2*w)*131072;
  const size_t kbase1 = (size_t)(b*16 + 2*w+1)*131072;

  __syncthreads();

  for (int t=0; t<32; ++t){
    const int j0 = jsb + t*32;
    f32x4 s0[2], s1[2];
    #pragma unroll
    for (int jf=0;jf<2;++jf){ s0[jf]=zero4(); s1[jf]=zero4(); }
    #pragma unroll
    for (int kf=0; kf<2; ++kf){
      #pragma unroll
      for (int jf=0; jf<2; ++jf){
        size_t off = (size_t)(j0 + jf*16 + lp)*64 + kf*32 + lg*8;
        bf16x8 k0 = *(const bf16x8*)(kk + kbase0 + off);
        bf16x8 k1 = *(const bf16x8*)(kk + kbase1 + off);
        s0[jf] = mfma16(qf[0][kf], k0, s0[jf]);
        s1[jf] = mfma16(qf[1][kf], k1, s1[jf]);
      }
    }
    #pragma unroll
    for (int jf=0;jf<2;++jf)
      #pragma unroll
      for (int r=0;r<4;++r){
        int ij = (lg*4+r)*32 + jf*16 + lp;
        unsigned int pk = (unsigned int)f2bf(s0[jf][r]) | ((unsigned int)f2bf(s1[jf][r])<<16);
        *(unsigned int*)(smem + ij*80 + w*4) = pk;
      }
    __syncthreads();

    unsigned int mku0 = *(const unsigned int*)(mask + b*2048 + j0 + lg*4);
    unsigned int mku1 = *(const unsigned int*)(mask + b*2048 + j0 + 16 + lg*4);
    #pragma unroll
    for (int cc=0; cc<4; ++cc){
      int c = w*4+cc;
      bf16x8 afr = *(const bf16x8*)(smem + (c*16+lp)*80 + lg*16);
      f32x4 pa = mfma16(afr, preB, zero4());
      int il = 2*w + (cc>>1);
      int jl = (cc&1)*16 + lg*4;
      float4 pb = *(const float4*)&pos_bias[((size_t)lp*2048 + (i0+il))*2048 + j0 + jl];
      unsigned int mku = (cc&1) ? mku1 : mku0;
      float va0 = pa[0] + pb.x + bpre_g + (((mku    )&255u) ? -1e30f : 0.f);
      float va1 = pa[1] + pb.y + bpre_g + (((mku>> 8)&255u) ? -1e30f : 0.f);
      float va2 = pa[2] + pb.z + bpre_g + (((mku>>16)&255u) ? -1e30f : 0.f);
      float va3 = pa[3] + pb.w + bpre_g + (((mku>>24)&255u) ? -1e30f : 0.f);
      int ii = cc>>1;
      int rowb = (c*16 + lg*4);
      *(unsigned short*)(smem + (rowb+0)*80 + lp*2) = f2bf(__expf(va0-mC[ii])*linvC[ii]);
      *(unsigned short*)(smem + (rowb+1)*80 + lp*2) = f2bf(__expf(va1-mC[ii])*linvC[ii]);
      *(unsigned short*)(smem + (rowb+2)*80 + lp*2) = f2bf(__expf(va2-mC[ii])*linvC[ii]);
      *(unsigned short*)(smem + (rowb+3)*80 + lp*2) = f2bf(__expf(va3-mC[ii])*linvC[ii]);
    }
    __syncthreads();

    #pragma unroll
    for (int cc=0; cc<4; ++cc){
      int c = w*4+cc;
      bf16x8 a2 = *(const bf16x8*)(smem + (c*16+lp)*80 + lg*16);
      f32x4 aa = mfma16(a2, postB, zero4());
      int il = 2*w + (cc>>1);
      int jl = (cc&1)*16 + lg*4;
      short4v av;
      av.x = (short)f2bf(aa[0]); av.y = (short)f2bf(aa[1]);
      av.z = (short)f2bf(aa[2]); av.w = (short)f2bf(aa[3]);
      *(short4v*)(smem + 40960 + (lp*16 + il)*80 + jl*2) = av;
    }
    __syncthreads();

    #pragma unroll
    for (int hh=0; hh<2; ++hh){
      int gg = 2*w+hh;
      bf16x8 af = *(const bf16x8*)(smem + 40960 + (gg*16+lp)*80 + lg*16);
      #pragma unroll
      for (int df=0; df<4; ++df){
        bf16x8 vf = *(const bf16x8*)(vt + ((size_t)(b*16+gg)*64 + df*16 + lp)*2048 + j0 + lg*8);
        oacc[hh][df] = mfma16(af, vf, oacc[hh][df]);
      }
    }
    __syncthreads();
  }

  float* po = js ? pout1 : pout0;
  #pragma unroll
  for (int hh=0; hh<2; ++hh){
    int gg = 2*w+hh;
    float bp = (js==0) ? bpost[gg] : 0.f;
    #pragma unroll
    for (int df=0; df<4; ++df){
      int d = df*16+lp;
      float vs = vsum[(b*16+gg)*64 + d];
      #pragma unroll
      for (int r=0;r<4;++r){
        po[((size_t)b*2048 + i0 + lg*4 + r)*1024 + gg*64 + d] = oacc[hh][df][r] + bp*vs;
      }
    }
  }
}

// ======================================================================
extern "C" void kernel_launch(void* const* d_in, const int* in_sizes, int n_in,
                              void* d_out, int out_size, void* d_ws, size_t ws_size,
                              hipStream_t stream)
{
  const float* x        = (const float*)d_in[0];
  const float* pos_bias = (const float*)d_in[1];
  const unsigned char* mask = (const unsigned char*)d_in[2];
  const float* Wqkv     = (const float*)d_in[3];
  const float* Wout     = (const float*)d_in[4];
  const float* Wpre     = (const float*)d_in[5];
  const float* bpre     = (const float*)d_in[6];
  const float* Wpost    = (const float*)d_in[7];
  const float* bpost    = (const float*)d_in[8];
  const float* temp     = (const float*)d_in[9];
  float* out = (float*)d_out;
  float* kv_out = out + 4194304;

  char* ws = (char*)d_ws;
  unsigned short* XB    = (unsigned short*)(ws + 0);
  unsigned short* WT    = (unsigned short*)(ws + 8388608);
  unsigned short* WOT   = (unsigned short*)(ws + 8388608);
  float*          PART_M= (float*)        (ws + 10485760);
  float*          PART_L= (float*)        (ws + 11534336);
  unsigned short* WPRE  = (unsigned short*)(ws + 12582912);
  unsigned short* WPRE2 = (unsigned short*)(ws + 12583424);
  unsigned short* WPOST = (unsigned short*)(ws + 12583936);
  float*          VSUM  = (float*)        (ws + 12584448);
  float*          MASKF = (float*)        (ws + 12593152);
  unsigned short* QKV   = (unsigned short*)(ws + 14680064);
  unsigned short* VT    = (unsigned short*)(ws + 14680064);
  float*          POUT0 = (float*)        (ws + 23068672);
  unsigned short* Q     = (unsigned short*)(ws + 39845888);
  unsigned short* KB    = (unsigned short*)(ws + 48234496);
  unsigned short* VB    = (unsigned short*)(ws + 56623104);
  float*          POUT1 = (float*)        (ws + 56623104);
  unsigned short* PB    = (unsigned short*)(ws + 75497472);   // 268.4 MB (new path only)
  unsigned short* AO    = XB;

  const int use_new = (ws_size >= (size_t)343932928);

  k_f32_to_bf16<<<4096, 256, 0, stream>>>(x, XB, 1048576);
  k_convT<<<dim3(96,32), 256, 0, stream>>>(Wqkv, WT, 1024, 3072);
  k_gemm<0><<<dim3(24,32), 256, 0, stream>>>(XB, WT, (void*)QKV, 4096, 3072, 1024);
  k_split_norm<<<16384, 256, 0, stream>>>(QKV, Q, KB, VB, kv_out);
  k_transpose_v<<<dim3(32,32), 256, 0, stream>>>(VB, VT);
  k_vsum<<<32, 256, 0, stream>>>(VB, VSUM);
  k_prep<<<1, 256, 0, stream>>>(Wpre, Wpost, temp, WPRE, WPRE2, WPOST);
  k_maskf<<<16, 256, 0, stream>>>(mask, MASKF);
  k_convT<<<dim3(32,32), 256, 0, stream>>>(Wout, WOT, 1024, 1024);

  if (use_new){
    k_score<<<1024, 512, 0, stream>>>(Q, KB, pos_bias, MASKF, WPRE2, bpre, PB, PART_L);
    k_mix<<<512, 512, 0, stream>>>(PB, VT, WPOST, bpost, VSUM, PART_L, POUT0, POUT1);
  } else {
    k_pass1f<<<1024, 512, 0, stream>>>(Q, KB, pos_bias, mask, WPRE, bpre, PART_M, PART_L);
    k_pass2f<<<512, 512, 0, stream>>>(Q, KB, VT, pos_bias, mask, WPRE, WPOST, bpre, bpost, VSUM,
                                      PART_M, PART_L, POUT0, POUT1);
  }
  k_combine<<<4096, 256, 0, stream>>>(POUT0, POUT1, AO);
  k_gemm<1><<<dim3(8,32), 256, 0, stream>>>(AO, WOT, d_out, 4096, 1024, 1024);
}

// Round 8
// 522.200 us; speedup vs baseline: 1.7789x; 1.6521x over previous
//
#include <hip/hip_runtime.h>
#include <stdint.h>

typedef __attribute__((ext_vector_type(8))) short bf16x8;
typedef __attribute__((ext_vector_type(4))) float f32x4;
typedef __attribute__((ext_vector_type(4))) short short4v;

#define DEV __device__ __forceinline__
#define L2E 1.4426950408889634f

DEV float bf2f(unsigned short s){ union{unsigned int u; float f;} x; x.u = ((unsigned int)s)<<16; return x.f; }
DEV unsigned short f2bf(float f){ union{float f; unsigned int u;} x; x.f = f; x.u += 0x7fffu + ((x.u>>16)&1u); return (unsigned short)(x.u>>16); }

DEV f32x4 mfma16(bf16x8 a, bf16x8 b, f32x4 c){
  return __builtin_amdgcn_mfma_f32_16x16x32_bf16(a, b, c, 0, 0, 0);
}
DEV f32x4 zero4(){ f32x4 z; z[0]=0.f; z[1]=0.f; z[2]=0.f; z[3]=0.f; return z; }
DEV bf16x8 zerob(){ bf16x8 z; z[0]=0;z[1]=0;z[2]=0;z[3]=0;z[4]=0;z[5]=0;z[6]=0;z[7]=0; return z; }
DEV float fexp2(float x){ float r; asm volatile("v_exp_f32 %0, %1" : "=v"(r) : "v"(x)); return r; }
DEV void barw(){ asm volatile("s_waitcnt lgkmcnt(0)" ::: "memory"); __builtin_amdgcn_s_barrier(); }

// ---------------- elementwise f32 -> bf16 ----------------
__global__ __launch_bounds__(256) void k_f32_to_bf16(const float* __restrict__ in, unsigned short* __restrict__ out, int n4){
  int i = blockIdx.x*256 + threadIdx.x;
  if (i < n4){
    float4 v = ((const float4*)in)[i];
    short4v o; o.x=(short)f2bf(v.x); o.y=(short)f2bf(v.y); o.z=(short)f2bf(v.z); o.w=(short)f2bf(v.w);
    ((short4v*)out)[i] = o;
  }
}

// ------------- f32 [R][C] -> bf16 transposed [C][R] -------------
__global__ __launch_bounds__(256) void k_convT(const float* __restrict__ in, unsigned short* __restrict__ out, int R, int Cc){
  __shared__ float t[32][33];
  int c0 = blockIdx.x*32, r0 = blockIdx.y*32;
  int tid = threadIdx.x;
  int row = tid>>3, col4 = (tid&7)*4;
  float4 v = *(const float4*)&in[(size_t)(r0+row)*Cc + c0 + col4];
  t[row][col4+0]=v.x; t[row][col4+1]=v.y; t[row][col4+2]=v.z; t[row][col4+3]=v.w;
  __syncthreads();
  short4v o;
  o.x=(short)f2bf(t[col4+0][row]); o.y=(short)f2bf(t[col4+1][row]);
  o.z=(short)f2bf(t[col4+2][row]); o.w=(short)f2bf(t[col4+3][row]);
  *(short4v*)&out[(size_t)(c0+row)*R + r0 + col4] = o;
}

// ------------- small prep -------------
__global__ __launch_bounds__(256) void k_prep(const float* __restrict__ wpre, const float* __restrict__ wpost,
                                              const float* __restrict__ temp,
                                              unsigned short* __restrict__ wpre_t,
                                              unsigned short* __restrict__ wpre_t2,
                                              unsigned short* __restrict__ wpost_b){
  int t = threadIdx.x;
  float T = temp[0];
  wpre_t[t]  = f2bf(wpre[t]*T);
  wpre_t2[t] = f2bf(wpre[t]*T*L2E);
  wpost_b[t] = f2bf(wpost[t]);
}

// ------------- mask bytes -> f32 addend -------------
__global__ __launch_bounds__(256) void k_maskf(const unsigned char* __restrict__ mask, float* __restrict__ maskf){
  int i = blockIdx.x*256 + threadIdx.x;
  if (i < 4096) maskf[i] = mask[i] ? -1e30f : 0.f;
}

// ------------- GEMM -------------
template<int OUTF>
__global__ __launch_bounds__(256,2) void k_gemm(const unsigned short* __restrict__ A, const unsigned short* __restrict__ Bt,
                                                void* __restrict__ Cv, int M, int Nn, int K){
  __shared__ unsigned short As[128][72];
  __shared__ unsigned short Bs[128][72];
  int tid = threadIdx.x;
  int n0 = blockIdx.x*128, m0 = blockIdx.y*128;
  int w = tid>>6, lane = tid&63, lg = lane>>4, lp = lane&15;
  int wm = (w>>1)*64, wn = (w&1)*64;
  f32x4 acc[4][4];
  #pragma unroll
  for (int i=0;i<4;++i)
    #pragma unroll
    for (int j=0;j<4;++j) acc[i][j] = zero4();

  for (int kt=0; kt<K; kt+=64){
    #pragma unroll
    for (int cch=0; cch<4; ++cch){
      int e = tid + cch*256; int r = e>>3, cl = (e&7)*8;
      *(bf16x8*)&As[r][cl] = *(const bf16x8*)&A[(size_t)(m0+r)*K + kt + cl];
      *(bf16x8*)&Bs[r][cl] = *(const bf16x8*)&Bt[(size_t)(n0+r)*K + kt + cl];
    }
    __syncthreads();
    #pragma unroll
    for (int ks=0; ks<2; ++ks){
      bf16x8 a[4], b[4];
      #pragma unroll
      for (int mi=0; mi<4; ++mi) a[mi] = *(const bf16x8*)&As[wm+mi*16+lp][ks*32 + lg*8];
      #pragma unroll
      for (int ni=0; ni<4; ++ni) b[ni] = *(const bf16x8*)&Bs[wn+ni*16+lp][ks*32 + lg*8];
      #pragma unroll
      for (int mi=0; mi<4; ++mi)
        #pragma unroll
        for (int ni=0; ni<4; ++ni)
          acc[mi][ni] = mfma16(a[mi], b[ni], acc[mi][ni]);
    }
    __syncthreads();
  }
  #pragma unroll
  for (int mi=0; mi<4; ++mi)
    #pragma unroll
    for (int ni=0; ni<4; ++ni)
      #pragma unroll
      for (int r=0; r<4; ++r){
        int row = m0+wm+mi*16+lg*4+r, col = n0+wn+ni*16+lp;
        if (OUTF) ((float*)Cv)[(size_t)row*Nn+col] = acc[mi][ni][r];
        else ((unsigned short*)Cv)[(size_t)row*Nn+col] = f2bf(acc[mi][ni][r]);
      }
}

// ------------- split qkv, l2norm q/k -------------
__global__ __launch_bounds__(256) void k_split_norm(const unsigned short* __restrict__ qkv,
                                                    unsigned short* __restrict__ q, unsigned short* __restrict__ k,
                                                    unsigned short* __restrict__ v, float* __restrict__ kv_out){
  int w = threadIdx.x>>6, lane = threadIdx.x&63;
  int widx = blockIdx.x*4 + w;
  int h = widx & 15; int bn = widx >> 4;
  int b = bn >> 11; int n = bn & 2047;
  size_t base = (size_t)bn*3072 + h*192 + lane*3;
  float qv = bf2f(qkv[base]), kvv = bf2f(qkv[base+1]), vv = bf2f(qkv[base+2]);
  float nq = qv*qv, nk = kvv*kvv;
  #pragma unroll
  for (int m=1; m<64; m<<=1){ nq += __shfl_xor(nq, m); nk += __shfl_xor(nk, m); }
  float qn = qv / fmaxf(sqrtf(nq), 1e-12f);
  float kn = kvv / fmaxf(sqrtf(nk), 1e-12f);
  size_t idx = ((size_t)(b*16+h)*2048 + n)*64 + lane;
  q[idx] = f2bf(qn); k[idx] = f2bf(kn); v[idx] = f2bf(vv);
  kv_out[idx] = kn;
  kv_out[4194304 + idx] = vv;
}

// ------------- v -> vt transposed -------------
__global__ __launch_bounds__(256) void k_transpose_v(const unsigned short* __restrict__ v, unsigned short* __restrict__ vt){
  __shared__ unsigned short t[64][72];
  int bh = blockIdx.y; int n0 = blockIdx.x*64;
  int tid = threadIdx.x;
  #pragma unroll
  for (int cch=0; cch<2; ++cch){
    int e = tid + cch*256; int r = e>>3, c8 = (e&7)*8;
    *(bf16x8*)&t[r][c8] = *(const bf16x8*)&v[((size_t)bh*2048 + n0 + r)*64 + c8];
  }
  __syncthreads();
  #pragma unroll
  for (int cch=0; cch<2; ++cch){
    int e = tid + cch*256; int d = e>>3, nn8 = (e&7)*8;
    bf16x8 o;
    #pragma unroll
    for (int i=0;i<8;++i) o[i] = (short)t[nn8+i][d];
    *(bf16x8*)&vt[((size_t)bh*64 + d)*2048 + n0 + nn8] = o;
  }
}

// ------------- vsum -------------
__global__ __launch_bounds__(256) void k_vsum(const unsigned short* __restrict__ v, float* __restrict__ vsum){
  int bg = blockIdx.x;
  int d = threadIdx.x & 63, part = threadIdx.x>>6;
  float s = 0.f;
  for (int n = part*512; n < part*512+512; ++n) s += bf2f(v[((size_t)bg*2048 + n)*64 + d]);
  __shared__ float red[4][64];
  red[part][d] = s; __syncthreads();
  if (part==0) vsum[bg*64 + d] = red[0][d]+red[1][d]+red[2][d]+red[3][d];
}

// =================================================================
// k_score: single sweep; round-5 body + S double-buffer (1 barrier/tile)
// grid 1024: bid -> (b, it, js4). LDS = 2 x (512 rows x 40B) = 40KB.
// =================================================================
__global__ __launch_bounds__(512,4) void k_score(
    const unsigned short* __restrict__ q,
    const unsigned short* __restrict__ kk,
    const float* __restrict__ pos_bias,
    const float* __restrict__ maskf,
    const unsigned short* __restrict__ wpre_t2,
    const float* __restrict__ bpre,
    unsigned short* __restrict__ Pb,
    float* __restrict__ part_l)
{
  __shared__ __align__(16) char smem[40960];
  const int tid = threadIdx.x;
  const int w = tid>>6, lane = tid&63, lg = lane>>4, lp = lane&15;
  const int bid = blockIdx.x;
  const int qd = bid>>4, r2 = bid&15;
  const int b = r2>>3, n = qd*8 + (r2&7);
  const int it = n>>2, js = n&3;
  const int i0 = it*16, jsb = js*512;

  bf16x8 qf[2][2];
  #pragma unroll
  for (int hh=0; hh<2; ++hh){
    const unsigned short* qb = q + ((size_t)(b*16+2*w+hh)*2048 + i0 + lp)*64;
    qf[hh][0] = *(const bf16x8*)(qb + lg*8);
    qf[hh][1] = *(const bf16x8*)(qb + 32 + lg*8);
  }
  bf16x8 preA = zerob();
  if (lg < 2) preA = *(const bf16x8*)&wpre_t2[lp*16 + lg*8];
  float bpre_s[4];
  #pragma unroll
  for (int r=0;r<4;++r) bpre_s[r] = bpre[lg*4+r]*L2E - 32.0f;

  float sacc[2][4];
  #pragma unroll
  for (int ii=0;ii<2;++ii)
    #pragma unroll
    for (int r=0;r<4;++r) sacc[ii][r] = 0.f;

  const size_t kbase0 = (size_t)(b*16 + 2*w)*131072;
  const size_t kbase1 = (size_t)(b*16 + 2*w+1)*131072;

  // prefetch K(0)
  bf16x8 k0v[4], k1v[4];
  #pragma unroll
  for (int kf=0; kf<2; ++kf)
    #pragma unroll
    for (int jf=0; jf<2; ++jf){
      size_t off = (size_t)(jsb + jf*16 + lp)*64 + kf*32 + lg*8;
      k0v[kf*2+jf] = *(const bf16x8*)(kk + kbase0 + off);
      k1v[kf*2+jf] = *(const bf16x8*)(kk + kbase1 + off);
    }

  for (int t=0; t<16; ++t){
    const int j0 = jsb + t*32;
    const int j0n = jsb + ((t+1)&15)*32;
    char* sbuf = smem + (t&1)*20480;
    // this tile's pos_bias + mask (issued first; consumed after barrier)
    float pbt[4][4];
    #pragma unroll
    for (int cc=0; cc<4; ++cc){
      int il = 2*w + (cc>>1);
      int jl = (cc&1)*16 + lp;
      #pragma unroll
      for (int r=0;r<4;++r)
        pbt[cc][r] = pos_bias[(size_t)(lg*4+r)*4194304 + (size_t)(i0+il)*2048 + j0 + jl];
    }
    float mk0 = maskf[b*2048 + j0 + lp];
    float mk1 = maskf[b*2048 + j0 + 16 + lp];

    // QK (K prefetched last tile)
    f32x4 s0[2], s1[2];
    #pragma unroll
    for (int jf=0;jf<2;++jf){ s0[jf]=zero4(); s1[jf]=zero4(); }
    #pragma unroll
    for (int kf=0; kf<2; ++kf)
      #pragma unroll
      for (int jf=0; jf<2; ++jf){
        s0[jf] = mfma16(qf[0][kf], k0v[kf*2+jf], s0[jf]);
        s1[jf] = mfma16(qf[1][kf], k1v[kf*2+jf], s1[jf]);
      }
    // S write (40B rows)
    #pragma unroll
    for (int jf=0;jf<2;++jf)
      #pragma unroll
      for (int r=0;r<4;++r){
        int ij = (lg*4+r)*32 + jf*16 + lp;
        unsigned int pk = (unsigned int)f2bf(s0[jf][r]) | ((unsigned int)f2bf(s1[jf][r])<<16);
        *(unsigned int*)(sbuf + ij*40 + w*4) = pk;
      }
    // K prefetch next tile
    #pragma unroll
    for (int kf=0; kf<2; ++kf)
      #pragma unroll
      for (int jf=0; jf<2; ++jf){
        size_t off = (size_t)(j0n + jf*16 + lp)*64 + kf*32 + lg*8;
        k0v[kf*2+jf] = *(const bf16x8*)(kk + kbase0 + off);
        k1v[kf*2+jf] = *(const bf16x8*)(kk + kbase1 + off);
      }
    barw();   // single barrier per tile (dbuf makes second one unnecessary)

    // premix + exp2 + Pb store
    #pragma unroll
    for (int cc=0; cc<4; ++cc){
      int c = w*4+cc;
      int il = 2*w + (cc>>1);
      int jl = (cc&1)*16 + lp;
      bf16x8 sfrag = zerob();
      if (lg < 2) sfrag = *(const bf16x8*)(sbuf + (c*16+lp)*40 + lg*16);
      f32x4 pa = mfma16(preA, sfrag, zero4());
      float mkj = (cc&1) ? mk1 : mk0;
      float pv0 = fexp2(fmaf(pbt[cc][0], L2E, pa[0] + bpre_s[0] + mkj));
      float pv1 = fexp2(fmaf(pbt[cc][1], L2E, pa[1] + bpre_s[1] + mkj));
      float pv2 = fexp2(fmaf(pbt[cc][2], L2E, pa[2] + bpre_s[2] + mkj));
      float pv3 = fexp2(fmaf(pbt[cc][3], L2E, pa[3] + bpre_s[3] + mkj));
      sacc[cc>>1][0] += pv0; sacc[cc>>1][1] += pv1;
      sacc[cc>>1][2] += pv2; sacc[cc>>1][3] += pv3;
      short4v p4;
      p4.x = (short)f2bf(pv0); p4.y = (short)f2bf(pv1);
      p4.z = (short)f2bf(pv2); p4.w = (short)f2bf(pv3);
      *(short4v*)&Pb[(((size_t)(b*2048 + i0+il)*2048) + j0 + jl)*16 + lg*4] = p4;
    }
  }

  #pragma unroll
  for (int ii=0;ii<2;++ii)
    #pragma unroll
    for (int r=0;r<4;++r){
      float v = sacc[ii][r];
      #pragma unroll
      for (int m=1; m<16; m<<=1) v += __shfl_xor(v, m);
      sacc[ii][r] = v;
    }
  if (lp == 0){
    int base = ((b*128+it)*4 + js)*256;
    #pragma unroll
    for (int ii=0;ii<2;++ii){
      float4 st; st.x = sacc[ii][0]; st.y = sacc[ii][1]; st.z = sacc[ii][2]; st.w = sacc[ii][3];
      *(float4*)&part_l[base + (2*w+ii)*16 + lg*4] = st;
    }
  }
}

// =================================================================
// k_mix: round-5 body + Al double-buffer (1 barrier/tile)
// grid 512: bid -> (b, it, js2). LDS = 2x16KB Al + 1KB linv.
// =================================================================
__global__ __launch_bounds__(512,4) void k_mix(
    const unsigned short* __restrict__ Pb,
    const unsigned short* __restrict__ vt,
    const unsigned short* __restrict__ wpost_b,
    const float* __restrict__ bpost,
    const float* __restrict__ vsum,
    const float* __restrict__ part_l,
    float* __restrict__ pout0,
    float* __restrict__ pout1)
{
  __shared__ __align__(16) char smem[33792];
  float* linv = (float*)(smem + 32768);
  const int tid = threadIdx.x;
  const int w = tid>>6, lane = tid&63, lg = lane>>4, lp = lane&15;
  const int bid = blockIdx.x;
  const int qd = bid>>4, r2 = bid&15;
  const int b = r2>>3, n = qd*8 + (r2&7);
  const int it = n>>1, js = n&1;
  const int i0 = it*16, jsb = js*1024;

  if (tid < 256){
    int base = ((b*128+it)*4)*256 + tid;
    float sum = part_l[base] + part_l[base+256] + part_l[base+512] + part_l[base+768];
    linv[tid] = 1.f/sum;
  }
  __syncthreads();

  bf16x8 postB[2];
  #pragma unroll
  for (int ii=0;ii<2;++ii){
    postB[ii] = zerob();
    if (lg < 2){
      bf16x8 wf = *(const bf16x8*)&wpost_b[lp*16 + lg*8];
      int i = 2*w+ii;
      #pragma unroll
      for (int e=0;e<8;++e){
        float vsc = bf2f((unsigned short)wf[e]) * linv[i*16 + lg*8 + e];
        postB[ii][e] = (short)f2bf(vsc);
      }
    }
  }

  f32x4 oacc[2][4];
  #pragma unroll
  for (int hh=0; hh<2; ++hh)
    #pragma unroll
    for (int df=0; df<4; ++df) oacc[hh][df] = zero4();

  __syncthreads();

  for (int t=0; t<32; ++t){
    const int j0 = jsb + t*32;
    char* abuf = smem + (t&1)*16384;
    // Pb loads for this tile
    bf16x8 pfr[4];
    #pragma unroll
    for (int cc=0; cc<4; ++cc){
      int il = 2*w + (cc>>1);
      pfr[cc] = zerob();
      if (lg < 2)
        pfr[cc] = *(const bf16x8*)&Pb[(((size_t)(b*2048 + i0+il)*2048) + j0 + (cc&1)*16 + lp)*16 + lg*8];
    }
    // V loads for this tile (consumed after barrier)
    bf16x8 vfr[2][4];
    #pragma unroll
    for (int hh=0; hh<2; ++hh)
      #pragma unroll
      for (int df=0; df<4; ++df)
        vfr[hh][df] = *(const bf16x8*)(vt + ((size_t)(b*16+2*w+hh)*64 + df*16 + lp)*2048 + j0 + lg*8);
    // postmix -> Al
    #pragma unroll
    for (int cc=0; cc<4; ++cc){
      int il = 2*w + (cc>>1);
      f32x4 aa = mfma16(pfr[cc], postB[cc>>1], zero4());
      short4v av;
      av.x = (short)f2bf(aa[0]); av.y = (short)f2bf(aa[1]);
      av.z = (short)f2bf(aa[2]); av.w = (short)f2bf(aa[3]);
      int row = lp*16 + il;
      int chunk = ((cc&1)*4 + lg) ^ ((lp ^ il)&6);
      *(short4v*)(abuf + row*64 + chunk*8) = av;
    }
    barw();   // single barrier per tile
    // PV
    #pragma unroll
    for (int hh=0; hh<2; ++hh){
      int gg = 2*w+hh;
      bf16x8 af = *(const bf16x8*)(abuf + (gg*16+lp)*64 + (((lg*2) ^ ((gg^lp)&6))*8));
      #pragma unroll
      for (int df=0; df<4; ++df)
        oacc[hh][df] = mfma16(af, vfr[hh][df], oacc[hh][df]);
    }
  }

  float* po = js ? pout1 : pout0;
  #pragma unroll
  for (int hh=0; hh<2; ++hh){
    int gg = 2*w+hh;
    float bp = (js==0) ? bpost[gg] : 0.f;
    #pragma unroll
    for (int df=0; df<4; ++df){
      int d = df*16+lp;
      float vs = vsum[(b*16+gg)*64 + d];
      #pragma unroll
      for (int r=0;r<4;++r){
        po[((size_t)b*2048 + i0 + lg*4 + r)*1024 + gg*64 + d] = oacc[hh][df][r] + bp*vs;
      }
    }
  }
}

// ------------- combine partial outputs -> bf16 attn_out -------------
__global__ __launch_bounds__(256) void k_combine(const float* __restrict__ p0, const float* __restrict__ p1,
                                                 unsigned short* __restrict__ ao){
  int i = blockIdx.x*256 + threadIdx.x;
  float4 a = ((const float4*)p0)[i];
  float4 c = ((const float4*)p1)[i];
  short4v o;
  o.x=(short)f2bf(a.x+c.x); o.y=(short)f2bf(a.y+c.y);
  o.z=(short)f2bf(a.z+c.z); o.w=(short)f2bf(a.w+c.w);
  ((short4v*)ao)[i] = o;
}

// =================================================================
// OLD PATH (fallback for small ws): two-pass recompute
// =================================================================
__global__ __launch_bounds__(512,6) void k_pass1f(
    const unsigned short* __restrict__ q,
    const unsigned short* __restrict__ kk,
    const float* __restrict__ pos_bias,
    const unsigned char* __restrict__ mask,
    const unsigned short* __restrict__ wpre_t,
    const float* __restrict__ bpre,
    float* __restrict__ part_m,
    float* __restrict__ part_l)
{
  __shared__ __align__(16) char smem[40960];
  const int tid = threadIdx.x;
  const int w = tid>>6, lane = tid&63, lg = lane>>4, lp = lane&15;
  const int bid = blockIdx.x;
  const int js = bid & 3, b = (bid>>2)&1, it = bid>>3;
  const int i0 = it*16, jsb = js*512;

  *(f32x4*)(smem + tid*80 + 32) = zero4();
  *(f32x4*)(smem + tid*80 + 48) = zero4();

  bf16x8 qf[2][2];
  #pragma unroll
  for (int hh=0; hh<2; ++hh){
    const unsigned short* qb = q + ((size_t)(b*16+2*w+hh)*2048 + i0 + lp)*64;
    qf[hh][0] = *(const bf16x8*)(qb + lg*8);
    qf[hh][1] = *(const bf16x8*)(qb + 32 + lg*8);
  }
  bf16x8 preB = zerob();
  if (lg < 2) preB = *(const bf16x8*)&wpre_t[lp*16 + lg*8];
  const float bpre_g = bpre[lp];

  float m[2], s[2];
  m[0] = -3.0e38f; m[1] = -3.0e38f; s[0] = 0.f; s[1] = 0.f;
  const size_t kbase0 = (size_t)(b*16 + 2*w)*131072;
  const size_t kbase1 = (size_t)(b*16 + 2*w+1)*131072;

  __syncthreads();

  for (int t=0; t<16; ++t){
    const int j0 = jsb + t*32;
    f32x4 s0[2], s1[2];
    #pragma unroll
    for (int jf=0;jf<2;++jf){ s0[jf]=zero4(); s1[jf]=zero4(); }
    #pragma unroll
    for (int kf=0; kf<2; ++kf){
      #pragma unroll
      for (int jf=0; jf<2; ++jf){
        size_t off = (size_t)(j0 + jf*16 + lp)*64 + kf*32 + lg*8;
        bf16x8 k0 = *(const bf16x8*)(kk + kbase0 + off);
        bf16x8 k1 = *(const bf16x8*)(kk + kbase1 + off);
        s0[jf] = mfma16(qf[0][kf], k0, s0[jf]);
        s1[jf] = mfma16(qf[1][kf], k1, s1[jf]);
      }
    }
    #pragma unroll
    for (int jf=0;jf<2;++jf)
      #pragma unroll
      for (int r=0;r<4;++r){
        int ij = (lg*4+r)*32 + jf*16 + lp;
        unsigned int pk = (unsigned int)f2bf(s0[jf][r]) | ((unsigned int)f2bf(s1[jf][r])<<16);
        *(unsigned int*)(smem + ij*80 + w*4) = pk;
      }
    __syncthreads();

    unsigned int mku0 = *(const unsigned int*)(mask + b*2048 + j0 + lg*4);
    unsigned int mku1 = *(const unsigned int*)(mask + b*2048 + j0 + 16 + lg*4);
    #pragma unroll
    for (int cc=0; cc<4; ++cc){
      int c = w*4+cc;
      bf16x8 afr = *(const bf16x8*)(smem + (c*16+lp)*80 + lg*16);
      f32x4 pa = mfma16(afr, preB, zero4());
      int il = 2*w + (cc>>1);
      int jl = (cc&1)*16 + lg*4;
      float4 pb = *(const float4*)&pos_bias[((size_t)lp*2048 + (i0+il))*2048 + j0 + jl];
      unsigned int mku = (cc&1) ? mku1 : mku0;
      float va0 = pa[0] + pb.x + bpre_g + (((mku    )&255u) ? -1e30f : 0.f);
      float va1 = pa[1] + pb.y + bpre_g + (((mku>> 8)&255u) ? -1e30f : 0.f);
      float va2 = pa[2] + pb.z + bpre_g + (((mku>>16)&255u) ? -1e30f : 0.f);
      float va3 = pa[3] + pb.w + bpre_g + (((mku>>24)&255u) ? -1e30f : 0.f);
      int ii = cc>>1;
      float vm = fmaxf(fmaxf(va0,va1), fmaxf(va2,va3));
      float nm = fmaxf(m[ii], vm);
      s[ii] = s[ii]*__expf(m[ii]-nm) + __expf(va0-nm)+__expf(va1-nm)+__expf(va2-nm)+__expf(va3-nm);
      m[ii] = nm;
    }
    __syncthreads();
  }

  #pragma unroll
  for (int ii=0; ii<2; ++ii){
    #pragma unroll
    for (int mk_=16; mk_<=32; mk_<<=1){
      float m2 = __shfl_xor(m[ii], mk_);
      float l2 = __shfl_xor(s[ii], mk_);
      float nm = fmaxf(m[ii], m2);
      s[ii] = s[ii]*__expf(m[ii]-nm) + l2*__expf(m2-nm);
      m[ii] = nm;
    }
  }
  if (lg == 0){
    int pidx = ((b*128+it)*4 + js)*256;
    #pragma unroll
    for (int ii=0; ii<2; ++ii){
      part_m[pidx + (2*w+ii)*16 + lp] = m[ii];
      part_l[pidx + (2*w+ii)*16 + lp] = s[ii];
    }
  }
}

__global__ __launch_bounds__(512,4) void k_pass2f(
    const unsigned short* __restrict__ q,
    const unsigned short* __restrict__ kk,
    const unsigned short* __restrict__ vt,
    const float* __restrict__ pos_bias,
    const unsigned char* __restrict__ mask,
    const unsigned short* __restrict__ wpre_t,
    const unsigned short* __restrict__ wpost_b,
    const float* __restrict__ bpre,
    const float* __restrict__ bpost,
    const float* __restrict__ vsum,
    const float* __restrict__ part_m,
    const float* __restrict__ part_l,
    float* __restrict__ pout0,
    float* __restrict__ pout1)
{
  __shared__ __align__(16) char smem[61440];
  const int tid = threadIdx.x;
  const int w = tid>>6, lane = tid&63, lg = lane>>4, lp = lane&15;
  const int bid = blockIdx.x;
  const int js = bid & 1, b = (bid>>1)&1, it = bid>>2;
  const int i0 = it*16, jsb = js*1024;

  *(f32x4*)(smem + tid*80 + 32) = zero4();
  *(f32x4*)(smem + tid*80 + 48) = zero4();

  bf16x8 qf[2][2];
  #pragma unroll
  for (int hh=0; hh<2; ++hh){
    const unsigned short* qb = q + ((size_t)(b*16+2*w+hh)*2048 + i0 + lp)*64;
    qf[hh][0] = *(const bf16x8*)(qb + lg*8);
    qf[hh][1] = *(const bf16x8*)(qb + 32 + lg*8);
  }
  bf16x8 preB = zerob(), postB = zerob();
  if (lg < 2){
    preB  = *(const bf16x8*)&wpre_t[lp*16 + lg*8];
    postB = *(const bf16x8*)&wpost_b[lp*16 + lg*8];
  }
  const float bpre_g = bpre[lp];

  float mC[2], linvC[2];
  {
    float lC[2]; mC[0]=mC[1]=-3.0e38f; lC[0]=lC[1]=0.f;
    int base = ((b*128+it)*4)*256;
    #pragma unroll
    for (int sj=0; sj<4; ++sj){
      #pragma unroll
      for (int ii=0; ii<2; ++ii){
        float mp  = part_m[base + sj*256 + (2*w+ii)*16 + lp];
        float lpv = part_l[base + sj*256 + (2*w+ii)*16 + lp];
        float nm = fmaxf(mC[ii], mp);
        lC[ii] = lC[ii]*__expf(mC[ii]-nm) + lpv*__expf(mp-nm);
        mC[ii] = nm;
      }
    }
    linvC[0] = 1.f/lC[0]; linvC[1] = 1.f/lC[1];
  }

  f32x4 oacc[2][4];
  #pragma unroll
  for (int hh=0; hh<2; ++hh)
    #pragma unroll
    for (int df=0; df<4; ++df) oacc[hh][df] = zero4();

  const size_t kbase0 = (size_t)(b*16 + 2*w)*131072;
  const size_t kbase1 = (size_t)(b*16 + 2*w+1)*131072;

  __syncthreads();

  for (int t=0; t<32; ++t){
    const int j0 = jsb + t*32;
    f32x4 s0[2], s1[2];
    #pragma unroll
    for (int jf=0;jf<2;++jf){ s0[jf]=zero4(); s1[jf]=zero4(); }
    #pragma unroll
    for (int kf=0; kf<2; ++kf){
      #pragma unroll
      for (int jf=0; jf<2; ++jf){
        size_t off = (size_t)(j0 + jf*16 + lp)*64 + kf*32 + lg*8;
        bf16x8 k0 = *(const bf16x8*)(kk + kbase0 + off);
        bf16x8 k1 = *(const bf16x8*)(kk + kbase1 + off);
        s0[jf] = mfma16(qf[0][kf], k0, s0[jf]);
        s1[jf] = mfma16(qf[1][kf], k1, s1[jf]);
      }
    }
    #pragma unroll
    for (int jf=0;jf<2;++jf)
      #pragma unroll
      for (int r=0;r<4;++r){
        int ij = (lg*4+r)*32 + jf*16 + lp;
        unsigned int pk = (unsigned int)f2bf(s0[jf][r]) | ((unsigned int)f2bf(s1[jf][r])<<16);
        *(unsigned int*)(smem + ij*80 + w*4) = pk;
      }
    __syncthreads();

    unsigned int mku0 = *(const unsigned int*)(mask + b*2048 + j0 + lg*4);
    unsigned int mku1 = *(const unsigned int*)(mask + b*2048 + j0 + 16 + lg*4);
    #pragma unroll
    for (int cc=0; cc<4; ++cc){
      int c = w*4+cc;
      bf16x8 afr = *(const bf16x8*)(smem + (c*16+lp)*80 + lg*16);
      f32x4 pa = mfma16(afr, preB, zero4());
      int il = 2*w + (cc>>1);
      int jl = (cc&1)*16 + lg*4;
      float4 pb = *(const float4*)&pos_bias[((size_t)lp*2048 + (i0+il))*2048 + j0 + jl];
      unsigned int mku = (cc&1) ? mku1 : mku0;
      float va0 = pa[0] + pb.x + bpre_g + (((mku    )&255u) ? -1e30f : 0.f);
      float va1 = pa[1] + pb.y + bpre_g + (((mku>> 8)&255u) ? -1e30f : 0.f);
      float va2 = pa[2] + pb.z + bpre_g + (((mku>>16)&255u) ? -1e30f : 0.f);
      float va3 = pa[3] + pb.w + bpre_g + (((mku>>24)&255u) ? -1e30f : 0.f);
      int ii = cc>>1;
      int rowb = (c*16 + lg*4);
      *(unsigned short*)(smem + (rowb+0)*80 + lp*2) = f2bf(__expf(va0-mC[ii])*linvC[ii]);
      *(unsigned short*)(smem + (rowb+1)*80 + lp*2) = f2bf(__expf(va1-mC[ii])*linvC[ii]);
      *(unsigned short*)(smem + (rowb+2)*80 + lp*2) = f2bf(__expf(va2-mC[ii])*linvC[ii]);
      *(unsigned short*)(smem + (rowb+3)*80 + lp*2) = f2bf(__expf(va3-mC[ii])*linvC[ii]);
    }
    __syncthreads();

    #pragma unroll
    for (int cc=0; cc<4; ++cc){
      int c = w*4+cc;
      bf16x8 a2 = *(const bf16x8*)(smem + (c*16+lp)*80 + lg*16);
      f32x4 aa = mfma16(a2, postB, zero4());
      int il = 2*w + (cc>>1);
      int jl = (cc&1)*16 + lg*4;
      short4v av;
      av.x = (short)f2bf(aa[0]); av.y = (short)f2bf(aa[1]);
      av.z = (short)f2bf(aa[2]); av.w = (short)f2bf(aa[3]);
      *(short4v*)(smem + 40960 + (lp*16 + il)*80 + jl*2) = av;
    }
    __syncthreads();

    #pragma unroll
    for (int hh=0; hh<2; ++hh){
      int gg = 2*w+hh;
      bf16x8 af = *(const bf16x8*)(smem + 40960 + (gg*16+lp)*80 + lg*16);
      #pragma unroll
      for (int df=0; df<4; ++df){
        bf16x8 vf = *(const bf16x8*)(vt + ((size_t)(b*16+gg)*64 + df*16 + lp)*2048 + j0 + lg*8);
        oacc[hh][df] = mfma16(af, vf, oacc[hh][df]);
      }
    }
    __syncthreads();
  }

  float* po = js ? pout1 : pout0;
  #pragma unroll
  for (int hh=0; hh<2; ++hh){
    int gg = 2*w+hh;
    float bp = (js==0) ? bpost[gg] : 0.f;
    #pragma unroll
    for (int df=0; df<4; ++df){
      int d = df*16+lp;
      float vs = vsum[(b*16+gg)*64 + d];
      #pragma unroll
      for (int r=0;r<4;++r){
        po[((size_t)b*2048 + i0 + lg*4 + r)*1024 + gg*64 + d] = oacc[hh][df][r] + bp*vs;
      }
    }
  }
}

// ======================================================================
extern "C" void kernel_launch(void* const* d_in, const int* in_sizes, int n_in,
                              void* d_out, int out_size, void* d_ws, size_t ws_size,
                              hipStream_t stream)
{
  const float* x        = (const float*)d_in[0];
  const float* pos_bias = (const float*)d_in[1];
  const unsigned char* mask = (const unsigned char*)d_in[2];
  const float* Wqkv     = (const float*)d_in[3];
  const float* Wout     = (const float*)d_in[4];
  const float* Wpre     = (const float*)d_in[5];
  const float* bpre     = (const float*)d_in[6];
  const float* Wpost    = (const float*)d_in[7];
  const float* bpost    = (const float*)d_in[8];
  const float* temp     = (const float*)d_in[9];
  float* out = (float*)d_out;
  float* kv_out = out + 4194304;

  char* ws = (char*)d_ws;
  unsigned short* XB    = (unsigned short*)(ws + 0);
  unsigned short* WT    = (unsigned short*)(ws + 8388608);
  unsigned short* WOT   = (unsigned short*)(ws + 8388608);
  float*          PART_M= (float*)        (ws + 10485760);
  float*          PART_L= (float*)        (ws + 11534336);
  unsigned short* WPRE  = (unsigned short*)(ws + 12582912);
  unsigned short* WPRE2 = (unsigned short*)(ws + 12583424);
  unsigned short* WPOST = (unsigned short*)(ws + 12583936);
  float*          VSUM  = (float*)        (ws + 12584448);
  float*          MASKF = (float*)        (ws + 12593152);
  unsigned short* QKV   = (unsigned short*)(ws + 14680064);
  unsigned short* VT    = (unsigned short*)(ws + 14680064);
  float*          POUT0 = (float*)        (ws + 23068672);
  unsigned short* Q     = (unsigned short*)(ws + 39845888);
  unsigned short* KB    = (unsigned short*)(ws + 48234496);
  unsigned short* VB    = (unsigned short*)(ws + 56623104);
  float*          POUT1 = (float*)        (ws + 56623104);
  unsigned short* PB    = (unsigned short*)(ws + 75497472);   // 268.4 MB (new path only)
  unsigned short* AO    = XB;

  const int use_new = (ws_size >= (size_t)343932928);

  k_f32_to_bf16<<<4096, 256, 0, stream>>>(x, XB, 1048576);
  k_convT<<<dim3(96,32), 256, 0, stream>>>(Wqkv, WT, 1024, 3072);
  k_gemm<0><<<dim3(24,32), 256, 0, stream>>>(XB, WT, (void*)QKV, 4096, 3072, 1024);
  k_split_norm<<<16384, 256, 0, stream>>>(QKV, Q, KB, VB, kv_out);
  k_transpose_v<<<dim3(32,32), 256, 0, stream>>>(VB, VT);
  k_vsum<<<32, 256, 0, stream>>>(VB, VSUM);
  k_prep<<<1, 256, 0, stream>>>(Wpre, Wpost, temp, WPRE, WPRE2, WPOST);
  k_maskf<<<16, 256, 0, stream>>>(mask, MASKF);
  k_convT<<<dim3(32,32), 256, 0, stream>>>(Wout, WOT, 1024, 1024);

  if (use_new){
    k_score<<<1024, 512, 0, stream>>>(Q, KB, pos_bias, MASKF, WPRE2, bpre, PB, PART_L);
    k_mix<<<512, 512, 0, stream>>>(PB, VT, WPOST, bpost, VSUM, PART_L, POUT0, POUT1);
  } else {
    k_pass1f<<<1024, 512, 0, stream>>>(Q, KB, pos_bias, mask, WPRE, bpre, PART_M, PART_L);
    k_pass2f<<<512, 512, 0, stream>>>(Q, KB, VT, pos_bias, mask, WPRE, WPOST, bpre, bpost, VSUM,
                                      PART_M, PART_L, POUT0, POUT1);
  }
  k_combine<<<4096, 256, 0, stream>>>(POUT0, POUT1, AO);
  k_gemm<1><<<dim3(8,32), 256, 0, stream>>>(AO, WOT, d_out, 4096, 1024, 1024);
}